// Round 6
// baseline (305.349 us; speedup 1.0000x reference)
//
#include <hip/hip_runtime.h>

typedef __bf16 bf16;
typedef __attribute__((ext_vector_type(8))) __bf16 bf16x8;
typedef __attribute__((ext_vector_type(4))) __bf16 bf16x4;
typedef __attribute__((ext_vector_type(4))) float f32x4;
typedef __attribute__((ext_vector_type(4))) float fvec4;

#define NB 2
#define SEQ 2048
#define DM 1024
#define NH 8
#define HD 128

// scale folded into Wq/bq: 1/sqrt(HD) * log2(e)
#define QSCL (0.08838834764831845f * 1.4426950408889634f)

#define AS1 __attribute__((address_space(1)))
#define AS3 __attribute__((address_space(3)))

// ---------------------------------------------------------------------------
// Kernel 0: prep.  z<3: convert q/k/v fp32 -> bf16.  z in [3,5]: transpose-
// convert W -> Wt bf16 (QSCL folded into Wq).  z==6 (block 0 only): mask
// encoding detect -> flag.   (verified round-5 version, unchanged)
// ---------------------------------------------------------------------------
__global__ __launch_bounds__(256) void prep_kernel(
    const float* __restrict__ qi, const float* __restrict__ ki,
    const float* __restrict__ vi,
    const float* __restrict__ Wq, const float* __restrict__ Wk,
    const float* __restrict__ Wv,
    const unsigned int* __restrict__ mask32,
    bf16* __restrict__ Xc, bf16* __restrict__ Wt,
    unsigned int* __restrict__ flag)
{
    const int z   = blockIdx.y;
    const int tid = threadIdx.x;
    __shared__ __align__(16) bf16 tile[64][80];  // 80: keeps 16B-aligned rows
    __shared__ unsigned int sred[256];

    if (z < 3) {
        const float* src = (z == 0) ? qi : (z == 1) ? ki : vi;
        bf16* dst = Xc + (size_t)z * ((size_t)NB * SEQ * DM);
        const size_t base = (size_t)blockIdx.x * 4096 + (size_t)tid * 16;
        fvec4 f[4];
        #pragma unroll
        for (int j = 0; j < 4; j++)
            f[j] = *(const fvec4*)(src + base + j * 4);
        bf16x8 h0, h1;
        #pragma unroll
        for (int e = 0; e < 8; e++) {
            h0[e] = (bf16)f[e >> 2][e & 3];
            h1[e] = (bf16)f[2 + (e >> 2)][e & 3];
        }
        *(bf16x8*)(dst + base)     = h0;
        *(bf16x8*)(dst + base + 8) = h1;
    } else if (z < 6) {
        if (blockIdx.x >= 256) return;
        const float* W = (z == 3) ? Wq : (z == 4) ? Wk : Wv;
        bf16* dst = Wt + (size_t)(z - 3) * ((size_t)DM * DM);
        const float scl = (z == 3) ? QSCL : 1.0f;
        const int n0 = (blockIdx.x & 15) * 64;
        const int k0 = (blockIdx.x >> 4) * 64;
        #pragma unroll
        for (int p = 0; p < 4; p++) {
            const int r = p * 16 + (tid >> 4);      // k row
            const int c = (tid & 15) * 4;           // n col
            const fvec4 wv = *(const fvec4*)(W + (size_t)(k0 + r) * DM + n0 + c);
            #pragma unroll
            for (int j = 0; j < 4; j++)
                tile[c + j][r] = (bf16)(wv[j] * scl);
        }
        __syncthreads();
        #pragma unroll
        for (int p = 0; p < 2; p++) {
            const int row = p * 32 + (tid >> 3);    // n row of output
            const int ch  = tid & 7;                // 8-elem k chunk
            const bf16x8 hv = *(const bf16x8*)(&tile[row][ch * 8]);
            *(bf16x8*)(dst + (size_t)(n0 + row) * DM + k0 + ch * 8) = hv;
        }
    } else {
        // mask encoding detect (byte-bool vs 32-bit-word bool), 1 block
        if (blockIdx.x != 0) return;
        unsigned int f = 0;
        for (int i = tid; i < 1024; i += 256) {
            const unsigned int w2 = mask32[i];
            if ((w2 & 0xFEFEFEFEu) == 0u && (w2 & 0xFFFFFF00u) != 0u) f = 1;
        }
        sred[tid] = f;
        __syncthreads();
        if (tid == 0) {
            unsigned int r = 0;
            for (int i = 0; i < 256; i++) r |= sred[i];
            *flag = r;
        }
    }
}

// ---------------------------------------------------------------------------
// Kernel 1: projection GEMM + vectorized mask pack (verified round-5 version,
// unchanged).
// ---------------------------------------------------------------------------
__global__ __launch_bounds__(256) void proj_kernel(
    const bf16* __restrict__ Xc, const bf16* __restrict__ Wt,
    const float* __restrict__ bq, const float* __restrict__ bk,
    const float* __restrict__ bv,
    bf16* __restrict__ Qo, bf16* __restrict__ Ko, bf16* __restrict__ Vto,
    const void* __restrict__ mask, const unsigned int* __restrict__ flag,
    unsigned long long* __restrict__ bits)
{
    __shared__ __align__(16) bf16 As[2][128 * 64];
    __shared__ __align__(16) bf16 Bs[2][128 * 64];

    const int pz = blockIdx.z;
    const int tid = threadIdx.x;

    if (pz == 3) {
        // ---- mask pack: 256 blocks x 256 threads x 8 iters x 16 elems ----
        const bool bytem = (*flag & 1u) != 0;
        const int wid = blockIdx.y * 8 + blockIdx.x;        // 0..255
        const int t   = wid * 256 + tid;                    // 0..65535
        unsigned short* const bits16o = (unsigned short*)bits;
        #pragma unroll 2
        for (int it = 0; it < 8; ++it) {
            const size_t e0 = ((size_t)it * 65536 + t) * 16;  // element base
            unsigned int b16 = 0;
            if (bytem) {
                const uint4 wv = *(const uint4*)((const unsigned char*)mask + e0);
                const unsigned int wd[4] = {wv.x, wv.y, wv.z, wv.w};
                #pragma unroll
                for (int j = 0; j < 4; j++) {
                    b16 |= ((wd[j] & 0x000000FFu) ? 1u : 0u) << (4 * j + 0);
                    b16 |= ((wd[j] & 0x0000FF00u) ? 1u : 0u) << (4 * j + 1);
                    b16 |= ((wd[j] & 0x00FF0000u) ? 1u : 0u) << (4 * j + 2);
                    b16 |= ((wd[j] & 0xFF000000u) ? 1u : 0u) << (4 * j + 3);
                }
            } else {
                const unsigned int* mw = (const unsigned int*)mask + e0;
                #pragma unroll
                for (int j = 0; j < 4; j++) {
                    const uint4 wv = *(const uint4*)(mw + 4 * j);
                    b16 |= (wv.x ? 1u : 0u) << (4 * j + 0);
                    b16 |= (wv.y ? 1u : 0u) << (4 * j + 1);
                    b16 |= (wv.z ? 1u : 0u) << (4 * j + 2);
                    b16 |= (wv.w ? 1u : 0u) << (4 * j + 3);
                }
            }
            bits16o[e0 >> 4] = (unsigned short)b16;
        }
        return;
    }

    const bf16* X  = Xc + (size_t)pz * ((size_t)NB * SEQ * DM);
    const bf16* Bt = Wt + (size_t)pz * ((size_t)DM * DM);
    const float* bias = (pz == 0) ? bq : (pz == 1) ? bk : bv;
    const float bscl  = (pz == 0) ? QSCL : 1.0f;
    bf16* dst = (pz == 0) ? Qo : (pz == 1) ? Ko : Vto;

    const int lane = tid & 63;
    const int w    = tid >> 6;
    const int q16  = lane >> 4;
    const int l15  = lane & 15;

    const int m0 = blockIdx.y * 128;
    const int n0 = blockIdx.x * 128;
    const int wm = (w >> 1) * 64;
    const int wn = (w & 1) * 64;

    auto stage = [&](int buf, int k0) {
        #pragma unroll
        for (int i = 0; i < 4; i++) {
            const int c   = i * 256 + tid;
            const int row = c >> 3;
            const int cir = c & 7;
            const bf16* src =
                X + (size_t)(m0 + row) * DM + k0 + ((cir ^ (row & 7)) << 3);
            __builtin_amdgcn_global_load_lds(
                (const AS1 void*)src,
                (AS3 void*)(&As[buf][c * 8]),
                16, 0, 0);
        }
        #pragma unroll
        for (int i = 0; i < 4; i++) {
            const int c   = i * 256 + tid;
            const int row = c >> 3;
            const int cir = c & 7;
            const bf16* src =
                Bt + (size_t)(n0 + row) * DM + k0 + ((cir ^ (row & 7)) << 3);
            __builtin_amdgcn_global_load_lds(
                (const AS1 void*)src,
                (AS3 void*)(&Bs[buf][c * 8]),
                16, 0, 0);
        }
    };

    f32x4 acc[4][4] = {};
    stage(0, 0);
    __syncthreads();
    int cur = 0;

    for (int kt = 0; kt < DM / 64; ++kt) {
        if (kt + 1 < DM / 64) stage(cur ^ 1, (kt + 1) * 64);
        const bf16* Asb = &As[cur][0];
        const bf16* Bsb = &Bs[cur][0];
        #pragma unroll
        for (int c2 = 0; c2 < 2; c2++) {
            bf16x8 af[4], bfr[4];
            #pragma unroll
            for (int mi = 0; mi < 4; mi++) {
                const int row = wm + mi * 16 + l15;
                af[mi] = *(const bf16x8*)(
                    Asb + row * 64 + (((c2 * 4 + q16) ^ (row & 7)) << 3));
            }
            #pragma unroll
            for (int ni = 0; ni < 4; ni++) {
                const int row = wn + ni * 16 + l15;
                bfr[ni] = *(const bf16x8*)(
                    Bsb + row * 64 + (((c2 * 4 + q16) ^ (row & 7)) << 3));
            }
            #pragma unroll
            for (int mi = 0; mi < 4; mi++)
                #pragma unroll
                for (int ni = 0; ni < 4; ni++)
                    acc[mi][ni] = __builtin_amdgcn_mfma_f32_16x16x32_bf16(
                        af[mi], bfr[ni], acc[mi][ni], 0, 0, 0);
        }
        __syncthreads();
        cur ^= 1;
    }

    float bias_v[4];
    #pragma unroll
    for (int ni = 0; ni < 4; ni++)
        bias_v[ni] = bias[n0 + wn + ni * 16 + l15];

    #pragma unroll
    for (int mi = 0; mi < 4; mi++) {
        #pragma unroll
        for (int ni = 0; ni < 4; ni++) {
            const int n  = n0 + wn + ni * 16 + l15;
            const int h  = n >> 7;
            const int hd = n & (HD - 1);
            #pragma unroll
            for (int r = 0; r < 4; r++) {
                const int m = m0 + wm + mi * 16 + q16 * 4 + r;
                const int b = m >> 11;
                const int s = m & (SEQ - 1);
                const float val = acc[mi][ni][r] + bias_v[ni] * bscl;
                size_t idx;
                if (pz == 2)
                    idx = ((size_t)(b * NH + h) * HD + hd) * SEQ + s;
                else
                    idx = ((size_t)(b * NH + h) * SEQ + s) * HD + hd;
                dst[idx] = (bf16)val;
            }
        }
    }
}

// ---------------------------------------------------------------------------
// Kernel 2: flash attention.  ONE change vs the verified 93.5us kernel:
// each wave now owns 32 q-rows (mi in {0,1}) instead of 16, block covers 128
// q-rows, grid halves to 256.  Every kf/vf LDS fragment read is reused for
// both mi -> per-output LDS traffic halves (the measured bottleneck: LDS-issue
// ~53us of 93us).  Staging, swizzles, mask indexing, softmax, P round-trip
// (stride 72), PV, epilogue preserved verbatim modulo the mi loop.
// ---------------------------------------------------------------------------
__global__ __launch_bounds__(256) void attn_kernel(
    const bf16* __restrict__ Q, const bf16* __restrict__ K,
    const bf16* __restrict__ Vt, const unsigned int* __restrict__ maskbits,
    float* __restrict__ out)
{
    __shared__ __align__(16) bf16 Ks[2][64 * 128];
    __shared__ __align__(16) bf16 Vs[2][128 * 64];
    __shared__ __align__(16) bf16 Ps[4][32 * 72];

    const int tid  = threadIdx.x;
    const int lane = tid & 63;
    const int w    = tid >> 6;
    const int q16  = lane >> 4;
    const int l15  = lane & 15;
    const int l3   = l15 & 7;

    const int b  = blockIdx.z;
    const int h  = blockIdx.y;
    const int q0 = blockIdx.x * 128;     // block now covers 128 q-rows
    const int bh = b * NH + h;
    const int wrow = w * 32;             // 32 rows per wave

    const bf16* Qb = Q  + (size_t)bh * SEQ * HD;
    const bf16* Kb = K  + (size_t)bh * SEQ * HD;
    const bf16* Vb = Vt + (size_t)bh * HD * SEQ;
    const unsigned long long* mb64 =
        (const unsigned long long*)maskbits + (size_t)b * (SEQ * SEQ / 64);
    const unsigned long long* mrow[2];
    #pragma unroll
    for (int mi = 0; mi < 2; mi++)
        mrow[mi] = mb64 +
            (size_t)(q0 + wrow + mi * 16 + q16 * 4) * (SEQ / 64);

    bf16x8 qf[2][4];
    #pragma unroll
    for (int mi = 0; mi < 2; mi++)
        #pragma unroll
        for (int c = 0; c < 4; c++)
            qf[mi][c] = *(const bf16x8*)(
                Qb + (size_t)(q0 + wrow + mi * 16 + l15) * HD + c * 32 + q16 * 8);

    f32x4 o[2][8] = {};
    float m_i[2][4], l_i[2][4];
    #pragma unroll
    for (int mi = 0; mi < 2; mi++)
        #pragma unroll
        for (int r = 0; r < 4; r++) { m_i[mi][r] = -__builtin_inff(); l_i[mi][r] = 0.f; }

    const float MASKV = -1.0e6f * QSCL;

    auto stage = [&](int buf, int k0) {
        bf16* kd = &Ks[buf][0];
        bf16* vd = &Vs[buf][0];
        #pragma unroll
        for (int i = 0; i < 4; i++) {
            const int c   = i * 256 + tid;
            const int row = c >> 4;
            const int cir = c & 15;
            const bf16* src =
                Kb + (size_t)(k0 + row) * HD + ((cir ^ (row & 7)) << 3);
            __builtin_amdgcn_global_load_lds(
                (const AS1 void*)src,
                (AS3 void*)(kd + c * 8),
                16, 0, 0);
        }
        #pragma unroll
        for (int i = 0; i < 4; i++) {
            const int c   = i * 256 + tid;
            const int d   = c >> 3;
            const int cir = c & 7;
            const bf16* src =
                Vb + (size_t)d * SEQ + k0 + ((cir ^ (d & 7)) << 3);
            __builtin_amdgcn_global_load_lds(
                (const AS1 void*)src,
                (AS3 void*)(vd + c * 8),
                16, 0, 0);
        }
    };

    stage(0, 0);
    __syncthreads();

    bf16* Pw = &Ps[w][0];
    int cur = 0;

    for (int kt = 0; kt < SEQ / 64; ++kt) {
        // mask words for this tile: issued first, consumed after QK^T
        // (QK compute covers the latency; no double-buffer needed)
        unsigned long long mw[2][4];
        #pragma unroll
        for (int mi = 0; mi < 2; mi++)
            #pragma unroll
            for (int r = 0; r < 4; r++)
                mw[mi][r] = mrow[mi][(size_t)r * (SEQ / 64) + kt];

        if (kt + 1 < SEQ / 64) stage(cur ^ 1, (kt + 1) * 64);

        const bf16* Ksb = &Ks[cur][0];
        const bf16* Vsb = &Vs[cur][0];

        // QK^T: each kf read feeds BOTH mi blocks (the amortization)
        f32x4 sf[2][4] = {};
        #pragma unroll
        for (int c = 0; c < 4; c++) {
            #pragma unroll
            for (int nf = 0; nf < 4; nf++) {
                const bf16x8 kf = *(const bf16x8*)(
                    Ksb + (nf * 16 + l15) * 128 + (((c * 4 + q16) ^ l3) << 3));
                #pragma unroll
                for (int mi = 0; mi < 2; mi++)
                    sf[mi][nf] = __builtin_amdgcn_mfma_f32_16x16x32_bf16(
                        qf[mi][c], kf, sf[mi][nf], 0, 0, 0);
            }
        }

        #pragma unroll
        for (int mi = 0; mi < 2; mi++)
            #pragma unroll
            for (int nf = 0; nf < 4; nf++)
                #pragma unroll
                for (int r = 0; r < 4; r++) {
                    const int mk = (int)((mw[mi][r] >> (nf * 16 + l15)) & 1ull);
                    sf[mi][nf][r] = mk ? MASKV : sf[mi][nf][r];
                }

        float alpha[2][4];
        bool need = false;
        #pragma unroll
        for (int mi = 0; mi < 2; mi++)
            #pragma unroll
            for (int r = 0; r < 4; r++) {
                float mx = fmaxf(fmaxf(sf[mi][0][r], sf[mi][1][r]),
                                 fmaxf(sf[mi][2][r], sf[mi][3][r]));
                #pragma unroll
                for (int off = 1; off < 16; off <<= 1)
                    mx = fmaxf(mx, __shfl_xor(mx, off, 16));
                const float mnew = fmaxf(m_i[mi][r], mx);
                alpha[mi][r] = __builtin_amdgcn_exp2f(m_i[mi][r] - mnew);
                need |= (mnew > m_i[mi][r]);
                m_i[mi][r] = mnew;
                float ps = 0.f;
                #pragma unroll
                for (int nf = 0; nf < 4; nf++) {
                    const float p = __builtin_amdgcn_exp2f(sf[mi][nf][r] - mnew);
                    sf[mi][nf][r] = p;
                    ps += p;
                }
                l_i[mi][r] = l_i[mi][r] * alpha[mi][r] + ps;
            }

        if (__ballot(need)) {
            #pragma unroll
            for (int mi = 0; mi < 2; mi++)
                #pragma unroll
                for (int df = 0; df < 8; df++)
                    #pragma unroll
                    for (int r = 0; r < 4; r++)
                        o[mi][df][r] *= alpha[mi][r];
        }

        #pragma unroll
        for (int mi = 0; mi < 2; mi++)
            #pragma unroll
            for (int nf = 0; nf < 4; nf++)
                #pragma unroll
                for (int r = 0; r < 4; r++)
                    Pw[(mi * 16 + q16 * 4 + r) * 72 + nf * 16 + l15] =
                        (bf16)sf[mi][nf][r];

        bf16x8 pf[2][2];
        #pragma unroll
        for (int mi = 0; mi < 2; mi++)
            #pragma unroll
            for (int cc = 0; cc < 2; cc++)
                pf[mi][cc] = *(const bf16x8*)(
                    Pw + (mi * 16 + l15) * 72 + cc * 32 + q16 * 8);

        // PV: each vf read feeds BOTH mi blocks
        #pragma unroll
        for (int df = 0; df < 8; df++) {
            #pragma unroll
            for (int cc = 0; cc < 2; cc++) {
                const bf16x8 vf = *(const bf16x8*)(
                    Vsb + (df * 16 + l15) * 64 + (((cc * 4 + q16) ^ l3) << 3));
                #pragma unroll
                for (int mi = 0; mi < 2; mi++)
                    o[mi][df] = __builtin_amdgcn_mfma_f32_16x16x32_bf16(
                        pf[mi][cc], vf, o[mi][df], 0, 0, 0);
            }
        }

        __syncthreads();
        cur ^= 1;
    }

    #pragma unroll
    for (int mi = 0; mi < 2; mi++)
        #pragma unroll
        for (int r = 0; r < 4; r++) {
            float ls = l_i[mi][r];
            #pragma unroll
            for (int off = 1; off < 16; off <<= 1)
                ls += __shfl_xor(ls, off, 16);
            l_i[mi][r] = 1.0f / ls;
        }
    #pragma unroll
    for (int mi = 0; mi < 2; mi++)
        #pragma unroll
        for (int df = 0; df < 8; df++) {
            #pragma unroll
            for (int r = 0; r < 4; r++) {
                const int qr = q0 + wrow + mi * 16 + q16 * 4 + r;
                out[((size_t)b * SEQ + qr) * DM + h * HD + df * 16 + l15] =
                    o[mi][df][r] * l_i[mi][r];
            }
        }
}

extern "C" void kernel_launch(void* const* d_in, const int* in_sizes, int n_in,
                              void* d_out, int out_size, void* d_ws, size_t ws_size,
                              hipStream_t stream) {
    const float* q    = (const float*)d_in[0];
    const float* k    = (const float*)d_in[1];
    const float* v    = (const float*)d_in[2];
    const void*  mask = d_in[3];
    const float* Wq   = (const float*)d_in[4];
    const float* bq   = (const float*)d_in[5];
    const float* Wk   = (const float*)d_in[6];
    const float* bk   = (const float*)d_in[7];
    const float* Wv   = (const float*)d_in[8];
    const float* bv   = (const float*)d_in[9];
    float* out = (float*)d_out;

    char* ws = (char*)d_ws;
    unsigned long long* bits = (unsigned long long*)ws;
    const size_t bits_bytes = (size_t)NB * SEQ * SEQ / 8;
    unsigned int* flag = (unsigned int*)(ws + bits_bytes);
    bf16* Qp = (bf16*)(ws + bits_bytes + 256);
    bf16* Kp = Qp + (size_t)NB * SEQ * DM;
    bf16* Vp = Kp + (size_t)NB * SEQ * DM;
    bf16* Xc = Vp + (size_t)NB * SEQ * DM;            // 24 MB
    bf16* Wt = Xc + (size_t)3 * NB * SEQ * DM;        //  6 MB

    // 3 launches: detect folded into prep (z==6), pack folded into proj (pz==3)
    prep_kernel<<<dim3(1024, 7), 256, 0, stream>>>(
        q, k, v, Wq, Wk, Wv, (const unsigned int*)mask, Xc, Wt, flag);

    dim3 pgrid(DM / 128, (NB * SEQ) / 128, 4);
    proj_kernel<<<pgrid, 256, 0, stream>>>(Xc, Wt, bq, bk, bv, Qp, Kp, Vp,
                                           mask, flag, bits);

    dim3 agrid(SEQ / 128, NH, NB);
    attn_kernel<<<agrid, 256, 0, stream>>>(Qp, Kp, Vp,
                                           (const unsigned int*)bits, out);
}

// Round 7
// 273.443 us; speedup vs baseline: 1.1167x; 1.1167x over previous
//
#include <hip/hip_runtime.h>

typedef __bf16 bf16;
typedef __attribute__((ext_vector_type(8))) __bf16 bf16x8;
typedef __attribute__((ext_vector_type(4))) __bf16 bf16x4;
typedef __attribute__((ext_vector_type(4))) float f32x4;
typedef __attribute__((ext_vector_type(4))) float fvec4;

#define NB 2
#define SEQ 2048
#define DM 1024
#define NH 8
#define HD 128

// scale folded into Wq/bq: 1/sqrt(HD) * log2(e)
#define QSCL (0.08838834764831845f * 1.4426950408889634f)

#define AS1 __attribute__((address_space(1)))
#define AS3 __attribute__((address_space(3)))

// DPP row_ror cross-lane move (VALU pipe; replaces ds_bpermute-based shfl).
// CTRL: 0x120+N = row_ror:N within each 16-lane row.
template <int CTRL>
__device__ __forceinline__ float dpp_ror(float x)
{
    return __builtin_bit_cast(float,
        __builtin_amdgcn_update_dpp(0, __builtin_bit_cast(int, x),
                                    CTRL, 0xF, 0xF, true));
}

// ---------------------------------------------------------------------------
// Kernel 0: prep.  z<3: convert q/k/v fp32 -> bf16.  z in [3,5]: transpose-
// convert W -> Wt bf16 (QSCL folded into Wq).  z==6 (block 0 only): mask
// encoding detect -> flag.   (verified round-5 version, unchanged)
// ---------------------------------------------------------------------------
__global__ __launch_bounds__(256) void prep_kernel(
    const float* __restrict__ qi, const float* __restrict__ ki,
    const float* __restrict__ vi,
    const float* __restrict__ Wq, const float* __restrict__ Wk,
    const float* __restrict__ Wv,
    const unsigned int* __restrict__ mask32,
    bf16* __restrict__ Xc, bf16* __restrict__ Wt,
    unsigned int* __restrict__ flag)
{
    const int z   = blockIdx.y;
    const int tid = threadIdx.x;
    __shared__ __align__(16) bf16 tile[64][80];  // 80: keeps 16B-aligned rows
    __shared__ unsigned int sred[256];

    if (z < 3) {
        const float* src = (z == 0) ? qi : (z == 1) ? ki : vi;
        bf16* dst = Xc + (size_t)z * ((size_t)NB * SEQ * DM);
        const size_t base = (size_t)blockIdx.x * 4096 + (size_t)tid * 16;
        fvec4 f[4];
        #pragma unroll
        for (int j = 0; j < 4; j++)
            f[j] = *(const fvec4*)(src + base + j * 4);
        bf16x8 h0, h1;
        #pragma unroll
        for (int e = 0; e < 8; e++) {
            h0[e] = (bf16)f[e >> 2][e & 3];
            h1[e] = (bf16)f[2 + (e >> 2)][e & 3];
        }
        *(bf16x8*)(dst + base)     = h0;
        *(bf16x8*)(dst + base + 8) = h1;
    } else if (z < 6) {
        if (blockIdx.x >= 256) return;
        const float* W = (z == 3) ? Wq : (z == 4) ? Wk : Wv;
        bf16* dst = Wt + (size_t)(z - 3) * ((size_t)DM * DM);
        const float scl = (z == 3) ? QSCL : 1.0f;
        const int n0 = (blockIdx.x & 15) * 64;
        const int k0 = (blockIdx.x >> 4) * 64;
        #pragma unroll
        for (int p = 0; p < 4; p++) {
            const int r = p * 16 + (tid >> 4);      // k row
            const int c = (tid & 15) * 4;           // n col
            const fvec4 wv = *(const fvec4*)(W + (size_t)(k0 + r) * DM + n0 + c);
            #pragma unroll
            for (int j = 0; j < 4; j++)
                tile[c + j][r] = (bf16)(wv[j] * scl);
        }
        __syncthreads();
        #pragma unroll
        for (int p = 0; p < 2; p++) {
            const int row = p * 32 + (tid >> 3);    // n row of output
            const int ch  = tid & 7;                // 8-elem k chunk
            const bf16x8 hv = *(const bf16x8*)(&tile[row][ch * 8]);
            *(bf16x8*)(dst + (size_t)(n0 + row) * DM + k0 + ch * 8) = hv;
        }
    } else {
        // mask encoding detect (byte-bool vs 32-bit-word bool), 1 block
        if (blockIdx.x != 0) return;
        unsigned int f = 0;
        for (int i = tid; i < 1024; i += 256) {
            const unsigned int w2 = mask32[i];
            if ((w2 & 0xFEFEFEFEu) == 0u && (w2 & 0xFFFFFF00u) != 0u) f = 1;
        }
        sred[tid] = f;
        __syncthreads();
        if (tid == 0) {
            unsigned int r = 0;
            for (int i = 0; i < 256; i++) r |= sred[i];
            *flag = r;
        }
    }
}

// ---------------------------------------------------------------------------
// Kernel 1: projection GEMM + vectorized mask pack (verified round-5 version,
// unchanged).
// ---------------------------------------------------------------------------
__global__ __launch_bounds__(256) void proj_kernel(
    const bf16* __restrict__ Xc, const bf16* __restrict__ Wt,
    const float* __restrict__ bq, const float* __restrict__ bk,
    const float* __restrict__ bv,
    bf16* __restrict__ Qo, bf16* __restrict__ Ko, bf16* __restrict__ Vto,
    const void* __restrict__ mask, const unsigned int* __restrict__ flag,
    unsigned long long* __restrict__ bits)
{
    __shared__ __align__(16) bf16 As[2][128 * 64];
    __shared__ __align__(16) bf16 Bs[2][128 * 64];

    const int pz = blockIdx.z;
    const int tid = threadIdx.x;

    if (pz == 3) {
        // ---- mask pack: 256 blocks x 256 threads x 8 iters x 16 elems ----
        const bool bytem = (*flag & 1u) != 0;
        const int wid = blockIdx.y * 8 + blockIdx.x;        // 0..255
        const int t   = wid * 256 + tid;                    // 0..65535
        unsigned short* const bits16o = (unsigned short*)bits;
        #pragma unroll 2
        for (int it = 0; it < 8; ++it) {
            const size_t e0 = ((size_t)it * 65536 + t) * 16;  // element base
            unsigned int b16 = 0;
            if (bytem) {
                const uint4 wv = *(const uint4*)((const unsigned char*)mask + e0);
                const unsigned int wd[4] = {wv.x, wv.y, wv.z, wv.w};
                #pragma unroll
                for (int j = 0; j < 4; j++) {
                    b16 |= ((wd[j] & 0x000000FFu) ? 1u : 0u) << (4 * j + 0);
                    b16 |= ((wd[j] & 0x0000FF00u) ? 1u : 0u) << (4 * j + 1);
                    b16 |= ((wd[j] & 0x00FF0000u) ? 1u : 0u) << (4 * j + 2);
                    b16 |= ((wd[j] & 0xFF000000u) ? 1u : 0u) << (4 * j + 3);
                }
            } else {
                const unsigned int* mw = (const unsigned int*)mask + e0;
                #pragma unroll
                for (int j = 0; j < 4; j++) {
                    const uint4 wv = *(const uint4*)(mw + 4 * j);
                    b16 |= (wv.x ? 1u : 0u) << (4 * j + 0);
                    b16 |= (wv.y ? 1u : 0u) << (4 * j + 1);
                    b16 |= (wv.z ? 1u : 0u) << (4 * j + 2);
                    b16 |= (wv.w ? 1u : 0u) << (4 * j + 3);
                }
            }
            bits16o[e0 >> 4] = (unsigned short)b16;
        }
        return;
    }

    const bf16* X  = Xc + (size_t)pz * ((size_t)NB * SEQ * DM);
    const bf16* Bt = Wt + (size_t)pz * ((size_t)DM * DM);
    const float* bias = (pz == 0) ? bq : (pz == 1) ? bk : bv;
    const float bscl  = (pz == 0) ? QSCL : 1.0f;
    bf16* dst = (pz == 0) ? Qo : (pz == 1) ? Ko : Vto;

    const int lane = tid & 63;
    const int w    = tid >> 6;
    const int q16  = lane >> 4;
    const int l15  = lane & 15;

    const int m0 = blockIdx.y * 128;
    const int n0 = blockIdx.x * 128;
    const int wm = (w >> 1) * 64;
    const int wn = (w & 1) * 64;

    auto stage = [&](int buf, int k0) {
        #pragma unroll
        for (int i = 0; i < 4; i++) {
            const int c   = i * 256 + tid;
            const int row = c >> 3;
            const int cir = c & 7;
            const bf16* src =
                X + (size_t)(m0 + row) * DM + k0 + ((cir ^ (row & 7)) << 3);
            __builtin_amdgcn_global_load_lds(
                (const AS1 void*)src,
                (AS3 void*)(&As[buf][c * 8]),
                16, 0, 0);
        }
        #pragma unroll
        for (int i = 0; i < 4; i++) {
            const int c   = i * 256 + tid;
            const int row = c >> 3;
            const int cir = c & 7;
            const bf16* src =
                Bt + (size_t)(n0 + row) * DM + k0 + ((cir ^ (row & 7)) << 3);
            __builtin_amdgcn_global_load_lds(
                (const AS1 void*)src,
                (AS3 void*)(&Bs[buf][c * 8]),
                16, 0, 0);
        }
    };

    f32x4 acc[4][4] = {};
    stage(0, 0);
    __syncthreads();
    int cur = 0;

    for (int kt = 0; kt < DM / 64; ++kt) {
        if (kt + 1 < DM / 64) stage(cur ^ 1, (kt + 1) * 64);
        const bf16* Asb = &As[cur][0];
        const bf16* Bsb = &Bs[cur][0];
        #pragma unroll
        for (int c2 = 0; c2 < 2; c2++) {
            bf16x8 af[4], bfr[4];
            #pragma unroll
            for (int mi = 0; mi < 4; mi++) {
                const int row = wm + mi * 16 + l15;
                af[mi] = *(const bf16x8*)(
                    Asb + row * 64 + (((c2 * 4 + q16) ^ (row & 7)) << 3));
            }
            #pragma unroll
            for (int ni = 0; ni < 4; ni++) {
                const int row = wn + ni * 16 + l15;
                bfr[ni] = *(const bf16x8*)(
                    Bsb + row * 64 + (((c2 * 4 + q16) ^ (row & 7)) << 3));
            }
            #pragma unroll
            for (int mi = 0; mi < 4; mi++)
                #pragma unroll
                for (int ni = 0; ni < 4; ni++)
                    acc[mi][ni] = __builtin_amdgcn_mfma_f32_16x16x32_bf16(
                        af[mi], bfr[ni], acc[mi][ni], 0, 0, 0);
        }
        __syncthreads();
        cur ^= 1;
    }

    float bias_v[4];
    #pragma unroll
    for (int ni = 0; ni < 4; ni++)
        bias_v[ni] = bias[n0 + wn + ni * 16 + l15];

    #pragma unroll
    for (int mi = 0; mi < 4; mi++) {
        #pragma unroll
        for (int ni = 0; ni < 4; ni++) {
            const int n  = n0 + wn + ni * 16 + l15;
            const int h  = n >> 7;
            const int hd = n & (HD - 1);
            #pragma unroll
            for (int r = 0; r < 4; r++) {
                const int m = m0 + wm + mi * 16 + q16 * 4 + r;
                const int b = m >> 11;
                const int s = m & (SEQ - 1);
                const float val = acc[mi][ni][r] + bias_v[ni] * bscl;
                size_t idx;
                if (pz == 2)
                    idx = ((size_t)(b * NH + h) * HD + hd) * SEQ + s;
                else
                    idx = ((size_t)(b * NH + h) * SEQ + s) * HD + hd;
                dst[idx] = (bf16)val;
            }
        }
    }
}

// ---------------------------------------------------------------------------
// Kernel 2: flash attention — geometry REVERTED to the verified 93.5us
// round-1 kernel (64 q-rows/block, 16 q-rows/wave, 8 waves/CU; round-6's
// 32 q/wave variant was latency-bound at 1 wave/SIMD).  Two micro-changes
// on top of the verified structure:
//   (1) row-max / row-sum reduces: __shfl_xor(.,16) [ds_bpermute, LDS pipe,
//       ~30cy latency, 16/tile/wave in the softmax critical path] replaced
//       with DPP row_ror + fmax/add (VALU pipe, ~2cy).  16-lane reduce
//       groups are exactly DPP rows (lanes q16*16..q16*16+15).
//   (2) T5 s_setprio(1) around the QK and PV MFMA clusters (the two
//       blocks/CU are independent -> m191 attn regime, +4-7%).
// ---------------------------------------------------------------------------
__global__ __launch_bounds__(256) void attn_kernel(
    const bf16* __restrict__ Q, const bf16* __restrict__ K,
    const bf16* __restrict__ Vt, const unsigned int* __restrict__ maskbits,
    float* __restrict__ out)
{
    __shared__ __align__(16) bf16 Ks[2][64 * 128];
    __shared__ __align__(16) bf16 Vs[2][128 * 64];
    __shared__ __align__(16) bf16 Ps[4][16 * 72];

    const int tid  = threadIdx.x;
    const int lane = tid & 63;
    const int w    = tid >> 6;
    const int q16  = lane >> 4;
    const int l15  = lane & 15;
    const int l3   = l15 & 7;

    const int b  = blockIdx.z;
    const int h  = blockIdx.y;
    const int q0 = blockIdx.x * 64;
    const int bh = b * NH + h;

    const bf16* Qb = Q  + (size_t)bh * SEQ * HD;
    const bf16* Kb = K  + (size_t)bh * SEQ * HD;
    const bf16* Vb = Vt + (size_t)bh * HD * SEQ;
    const unsigned long long* mb64 =
        (const unsigned long long*)maskbits + (size_t)b * (SEQ * SEQ / 64);
    const int qbase = q0 + w * 16 + q16 * 4;
    const unsigned long long* mrow = mb64 + (size_t)qbase * (SEQ / 64);

    const int qrow_a = q0 + w * 16 + l15;
    bf16x8 qf[4];
    #pragma unroll
    for (int c = 0; c < 4; c++)
        qf[c] = *(const bf16x8*)(Qb + (size_t)qrow_a * HD + c * 32 + q16 * 8);

    f32x4 o[8] = {};
    float m_i[4], l_i[4];
    #pragma unroll
    for (int r = 0; r < 4; r++) { m_i[r] = -__builtin_inff(); l_i[r] = 0.f; }

    const float MASKV = -1.0e6f * QSCL;

    auto stage = [&](int buf, int k0) {
        bf16* kd = &Ks[buf][0];
        bf16* vd = &Vs[buf][0];
        #pragma unroll
        for (int i = 0; i < 4; i++) {
            const int c   = i * 256 + tid;
            const int row = c >> 4;
            const int cir = c & 15;
            const bf16* src =
                Kb + (size_t)(k0 + row) * HD + ((cir ^ (row & 7)) << 3);
            __builtin_amdgcn_global_load_lds(
                (const AS1 void*)src,
                (AS3 void*)(kd + c * 8),
                16, 0, 0);
        }
        #pragma unroll
        for (int i = 0; i < 4; i++) {
            const int c   = i * 256 + tid;
            const int d   = c >> 3;
            const int cir = c & 7;
            const bf16* src =
                Vb + (size_t)d * SEQ + k0 + ((cir ^ (d & 7)) << 3);
            __builtin_amdgcn_global_load_lds(
                (const AS1 void*)src,
                (AS3 void*)(vd + c * 8),
                16, 0, 0);
        }
    };

    unsigned long long mwn[4];
    stage(0, 0);
    #pragma unroll
    for (int r = 0; r < 4; r++) mwn[r] = mrow[(size_t)r * (SEQ / 64)];
    __syncthreads();

    bf16* Pw = &Ps[w][0];
    int cur = 0;

    for (int kt = 0; kt < SEQ / 64; ++kt) {
        unsigned long long mw[4];
        #pragma unroll
        for (int r = 0; r < 4; r++) mw[r] = mwn[r];

        if (kt + 1 < SEQ / 64) stage(cur ^ 1, (kt + 1) * 64);
        const int ktn = (kt + 1) & (SEQ / 64 - 1);
        #pragma unroll
        for (int r = 0; r < 4; r++)
            mwn[r] = mrow[(size_t)r * (SEQ / 64) + ktn];

        const bf16* Ksb = &Ks[cur][0];
        const bf16* Vsb = &Vs[cur][0];

        f32x4 sf[4] = {};
        __builtin_amdgcn_s_setprio(1);
        #pragma unroll
        for (int c = 0; c < 4; c++) {
            #pragma unroll
            for (int nf = 0; nf < 4; nf++) {
                const bf16x8 kf = *(const bf16x8*)(
                    Ksb + (nf * 16 + l15) * 128 + (((c * 4 + q16) ^ l3) << 3));
                sf[nf] = __builtin_amdgcn_mfma_f32_16x16x32_bf16(
                    qf[c], kf, sf[nf], 0, 0, 0);
            }
        }
        __builtin_amdgcn_s_setprio(0);

        #pragma unroll
        for (int nf = 0; nf < 4; nf++)
            #pragma unroll
            for (int r = 0; r < 4; r++) {
                const int mk = (int)((mw[r] >> (nf * 16 + l15)) & 1ull);
                sf[nf][r] = mk ? MASKV : sf[nf][r];
            }

        float alpha[4];
        bool need = false;
        #pragma unroll
        for (int r = 0; r < 4; r++) {
            float mx = fmaxf(fmaxf(sf[0][r], sf[1][r]),
                             fmaxf(sf[2][r], sf[3][r]));
            // 16-lane max-reduce via DPP row_ror (VALU), replaces ds_bpermute
            mx = fmaxf(mx, dpp_ror<0x121>(mx));
            mx = fmaxf(mx, dpp_ror<0x122>(mx));
            mx = fmaxf(mx, dpp_ror<0x124>(mx));
            mx = fmaxf(mx, dpp_ror<0x128>(mx));
            const float mnew = fmaxf(m_i[r], mx);
            alpha[r] = __builtin_amdgcn_exp2f(m_i[r] - mnew);
            need |= (mnew > m_i[r]);
            m_i[r] = mnew;
            float ps = 0.f;
            #pragma unroll
            for (int nf = 0; nf < 4; nf++) {
                const float p = __builtin_amdgcn_exp2f(sf[nf][r] - mnew);
                sf[nf][r] = p;
                ps += p;
            }
            l_i[r] = l_i[r] * alpha[r] + ps;
        }

        if (__ballot(need)) {
            #pragma unroll
            for (int df = 0; df < 8; df++)
                #pragma unroll
                for (int r = 0; r < 4; r++)
                    o[df][r] *= alpha[r];
        }

        #pragma unroll
        for (int nf = 0; nf < 4; nf++)
            #pragma unroll
            for (int r = 0; r < 4; r++)
                Pw[(q16 * 4 + r) * 72 + nf * 16 + l15] = (bf16)sf[nf][r];

        bf16x8 pf[2];
        #pragma unroll
        for (int cc = 0; cc < 2; cc++)
            pf[cc] = *(const bf16x8*)(Pw + l15 * 72 + cc * 32 + q16 * 8);

        __builtin_amdgcn_s_setprio(1);
        #pragma unroll
        for (int df = 0; df < 8; df++) {
            #pragma unroll
            for (int cc = 0; cc < 2; cc++) {
                const bf16x8 vf = *(const bf16x8*)(
                    Vsb + (df * 16 + l15) * 64 + (((cc * 4 + q16) ^ l3) << 3));
                o[df] = __builtin_amdgcn_mfma_f32_16x16x32_bf16(
                    pf[cc], vf, o[df], 0, 0, 0);
            }
        }
        __builtin_amdgcn_s_setprio(0);

        __syncthreads();
        cur ^= 1;
    }

    #pragma unroll
    for (int r = 0; r < 4; r++) {
        float ls = l_i[r];
        // 16-lane sum-reduce via DPP row_ror
        ls += dpp_ror<0x121>(ls);
        ls += dpp_ror<0x122>(ls);
        ls += dpp_ror<0x124>(ls);
        ls += dpp_ror<0x128>(ls);
        l_i[r] = 1.0f / ls;
    }
    #pragma unroll
    for (int df = 0; df < 8; df++) {
        #pragma unroll
        for (int r = 0; r < 4; r++) {
            const int qr = q0 + w * 16 + q16 * 4 + r;
            out[((size_t)b * SEQ + qr) * DM + h * HD + df * 16 + l15] =
                o[df][r] * l_i[r];
        }
    }
}

extern "C" void kernel_launch(void* const* d_in, const int* in_sizes, int n_in,
                              void* d_out, int out_size, void* d_ws, size_t ws_size,
                              hipStream_t stream) {
    const float* q    = (const float*)d_in[0];
    const float* k    = (const float*)d_in[1];
    const float* v    = (const float*)d_in[2];
    const void*  mask = d_in[3];
    const float* Wq   = (const float*)d_in[4];
    const float* bq   = (const float*)d_in[5];
    const float* Wk   = (const float*)d_in[6];
    const float* bk   = (const float*)d_in[7];
    const float* Wv   = (const float*)d_in[8];
    const float* bv   = (const float*)d_in[9];
    float* out = (float*)d_out;

    char* ws = (char*)d_ws;
    unsigned long long* bits = (unsigned long long*)ws;
    const size_t bits_bytes = (size_t)NB * SEQ * SEQ / 8;
    unsigned int* flag = (unsigned int*)(ws + bits_bytes);
    bf16* Qp = (bf16*)(ws + bits_bytes + 256);
    bf16* Kp = Qp + (size_t)NB * SEQ * DM;
    bf16* Vp = Kp + (size_t)NB * SEQ * DM;
    bf16* Xc = Vp + (size_t)NB * SEQ * DM;            // 24 MB
    bf16* Wt = Xc + (size_t)3 * NB * SEQ * DM;        //  6 MB

    // 3 launches: detect folded into prep (z==6), pack folded into proj (pz==3)
    prep_kernel<<<dim3(1024, 7), 256, 0, stream>>>(
        q, k, v, Wq, Wk, Wv, (const unsigned int*)mask, Xc, Wt, flag);

    dim3 pgrid(DM / 128, (NB * SEQ) / 128, 4);
    proj_kernel<<<pgrid, 256, 0, stream>>>(Xc, Wt, bq, bk, bv, Qp, Kp, Vp,
                                           mask, flag, bits);

    dim3 agrid(SEQ / 64, NH, NB);
    attn_kernel<<<agrid, 256, 0, stream>>>(Qp, Kp, Vp,
                                           (const unsigned int*)bits, out);
}

// Round 8
// 267.865 us; speedup vs baseline: 1.1399x; 1.0208x over previous
//
#include <hip/hip_runtime.h>

typedef __bf16 bf16;
typedef __attribute__((ext_vector_type(8))) __bf16 bf16x8;
typedef __attribute__((ext_vector_type(4))) __bf16 bf16x4;
typedef __attribute__((ext_vector_type(4))) float f32x4;
typedef __attribute__((ext_vector_type(4))) float fvec4;

#define NB 2
#define SEQ 2048
#define DM 1024
#define NH 8
#define HD 128

// scale folded into Wq/bq: 1/sqrt(HD) * log2(e)
#define QSCL (0.08838834764831845f * 1.4426950408889634f)

#define AS1 __attribute__((address_space(1)))
#define AS3 __attribute__((address_space(3)))

// ---------------------------------------------------------------------------
// Kernel 0: prep.  z<3: convert q/k/v fp32 -> bf16.  z in [3,5]: transpose-
// convert W -> Wt bf16 (QSCL folded into Wq).  z==6 (block 0 only): mask
// encoding detect -> flag.   (verified round-5 version, unchanged)
// ---------------------------------------------------------------------------
__global__ __launch_bounds__(256) void prep_kernel(
    const float* __restrict__ qi, const float* __restrict__ ki,
    const float* __restrict__ vi,
    const float* __restrict__ Wq, const float* __restrict__ Wk,
    const float* __restrict__ Wv,
    const unsigned int* __restrict__ mask32,
    bf16* __restrict__ Xc, bf16* __restrict__ Wt,
    unsigned int* __restrict__ flag)
{
    const int z   = blockIdx.y;
    const int tid = threadIdx.x;
    __shared__ __align__(16) bf16 tile[64][80];  // 80: keeps 16B-aligned rows
    __shared__ unsigned int sred[256];

    if (z < 3) {
        const float* src = (z == 0) ? qi : (z == 1) ? ki : vi;
        bf16* dst = Xc + (size_t)z * ((size_t)NB * SEQ * DM);
        const size_t base = (size_t)blockIdx.x * 4096 + (size_t)tid * 16;
        fvec4 f[4];
        #pragma unroll
        for (int j = 0; j < 4; j++)
            f[j] = *(const fvec4*)(src + base + j * 4);
        bf16x8 h0, h1;
        #pragma unroll
        for (int e = 0; e < 8; e++) {
            h0[e] = (bf16)f[e >> 2][e & 3];
            h1[e] = (bf16)f[2 + (e >> 2)][e & 3];
        }
        *(bf16x8*)(dst + base)     = h0;
        *(bf16x8*)(dst + base + 8) = h1;
    } else if (z < 6) {
        if (blockIdx.x >= 256) return;
        const float* W = (z == 3) ? Wq : (z == 4) ? Wk : Wv;
        bf16* dst = Wt + (size_t)(z - 3) * ((size_t)DM * DM);
        const float scl = (z == 3) ? QSCL : 1.0f;
        const int n0 = (blockIdx.x & 15) * 64;
        const int k0 = (blockIdx.x >> 4) * 64;
        #pragma unroll
        for (int p = 0; p < 4; p++) {
            const int r = p * 16 + (tid >> 4);      // k row
            const int c = (tid & 15) * 4;           // n col
            const fvec4 wv = *(const fvec4*)(W + (size_t)(k0 + r) * DM + n0 + c);
            #pragma unroll
            for (int j = 0; j < 4; j++)
                tile[c + j][r] = (bf16)(wv[j] * scl);
        }
        __syncthreads();
        #pragma unroll
        for (int p = 0; p < 2; p++) {
            const int row = p * 32 + (tid >> 3);    // n row of output
            const int ch  = tid & 7;                // 8-elem k chunk
            const bf16x8 hv = *(const bf16x8*)(&tile[row][ch * 8]);
            *(bf16x8*)(dst + (size_t)(n0 + row) * DM + k0 + ch * 8) = hv;
        }
    } else {
        // mask encoding detect (byte-bool vs 32-bit-word bool), 1 block
        if (blockIdx.x != 0) return;
        unsigned int f = 0;
        for (int i = tid; i < 1024; i += 256) {
            const unsigned int w2 = mask32[i];
            if ((w2 & 0xFEFEFEFEu) == 0u && (w2 & 0xFFFFFF00u) != 0u) f = 1;
        }
        sred[tid] = f;
        __syncthreads();
        if (tid == 0) {
            unsigned int r = 0;
            for (int i = 0; i < 256; i++) r |= sred[i];
            *flag = r;
        }
    }
}

// ---------------------------------------------------------------------------
// Kernel 1: projection GEMM + vectorized mask pack (verified round-5 version,
// unchanged).
// ---------------------------------------------------------------------------
__global__ __launch_bounds__(256) void proj_kernel(
    const bf16* __restrict__ Xc, const bf16* __restrict__ Wt,
    const float* __restrict__ bq, const float* __restrict__ bk,
    const float* __restrict__ bv,
    bf16* __restrict__ Qo, bf16* __restrict__ Ko, bf16* __restrict__ Vto,
    const void* __restrict__ mask, const unsigned int* __restrict__ flag,
    unsigned long long* __restrict__ bits)
{
    __shared__ __align__(16) bf16 As[2][128 * 64];
    __shared__ __align__(16) bf16 Bs[2][128 * 64];

    const int pz = blockIdx.z;
    const int tid = threadIdx.x;

    if (pz == 3) {
        // ---- mask pack: 256 blocks x 256 threads x 8 iters x 16 elems ----
        const bool bytem = (*flag & 1u) != 0;
        const int wid = blockIdx.y * 8 + blockIdx.x;        // 0..255
        const int t   = wid * 256 + tid;                    // 0..65535
        unsigned short* const bits16o = (unsigned short*)bits;
        #pragma unroll 2
        for (int it = 0; it < 8; ++it) {
            const size_t e0 = ((size_t)it * 65536 + t) * 16;  // element base
            unsigned int b16 = 0;
            if (bytem) {
                const uint4 wv = *(const uint4*)((const unsigned char*)mask + e0);
                const unsigned int wd[4] = {wv.x, wv.y, wv.z, wv.w};
                #pragma unroll
                for (int j = 0; j < 4; j++) {
                    b16 |= ((wd[j] & 0x000000FFu) ? 1u : 0u) << (4 * j + 0);
                    b16 |= ((wd[j] & 0x0000FF00u) ? 1u : 0u) << (4 * j + 1);
                    b16 |= ((wd[j] & 0x00FF0000u) ? 1u : 0u) << (4 * j + 2);
                    b16 |= ((wd[j] & 0xFF000000u) ? 1u : 0u) << (4 * j + 3);
                }
            } else {
                const unsigned int* mw = (const unsigned int*)mask + e0;
                #pragma unroll
                for (int j = 0; j < 4; j++) {
                    const uint4 wv = *(const uint4*)(mw + 4 * j);
                    b16 |= (wv.x ? 1u : 0u) << (4 * j + 0);
                    b16 |= (wv.y ? 1u : 0u) << (4 * j + 1);
                    b16 |= (wv.z ? 1u : 0u) << (4 * j + 2);
                    b16 |= (wv.w ? 1u : 0u) << (4 * j + 3);
                }
            }
            bits16o[e0 >> 4] = (unsigned short)b16;
        }
        return;
    }

    const bf16* X  = Xc + (size_t)pz * ((size_t)NB * SEQ * DM);
    const bf16* Bt = Wt + (size_t)pz * ((size_t)DM * DM);
    const float* bias = (pz == 0) ? bq : (pz == 1) ? bk : bv;
    const float bscl  = (pz == 0) ? QSCL : 1.0f;
    bf16* dst = (pz == 0) ? Qo : (pz == 1) ? Ko : Vto;

    const int lane = tid & 63;
    const int w    = tid >> 6;
    const int q16  = lane >> 4;
    const int l15  = lane & 15;

    const int m0 = blockIdx.y * 128;
    const int n0 = blockIdx.x * 128;
    const int wm = (w >> 1) * 64;
    const int wn = (w & 1) * 64;

    auto stage = [&](int buf, int k0) {
        #pragma unroll
        for (int i = 0; i < 4; i++) {
            const int c   = i * 256 + tid;
            const int row = c >> 3;
            const int cir = c & 7;
            const bf16* src =
                X + (size_t)(m0 + row) * DM + k0 + ((cir ^ (row & 7)) << 3);
            __builtin_amdgcn_global_load_lds(
                (const AS1 void*)src,
                (AS3 void*)(&As[buf][c * 8]),
                16, 0, 0);
        }
        #pragma unroll
        for (int i = 0; i < 4; i++) {
            const int c   = i * 256 + tid;
            const int row = c >> 3;
            const int cir = c & 7;
            const bf16* src =
                Bt + (size_t)(n0 + row) * DM + k0 + ((cir ^ (row & 7)) << 3);
            __builtin_amdgcn_global_load_lds(
                (const AS1 void*)src,
                (AS3 void*)(&Bs[buf][c * 8]),
                16, 0, 0);
        }
    };

    f32x4 acc[4][4] = {};
    stage(0, 0);
    __syncthreads();
    int cur = 0;

    for (int kt = 0; kt < DM / 64; ++kt) {
        if (kt + 1 < DM / 64) stage(cur ^ 1, (kt + 1) * 64);
        const bf16* Asb = &As[cur][0];
        const bf16* Bsb = &Bs[cur][0];
        #pragma unroll
        for (int c2 = 0; c2 < 2; c2++) {
            bf16x8 af[4], bfr[4];
            #pragma unroll
            for (int mi = 0; mi < 4; mi++) {
                const int row = wm + mi * 16 + l15;
                af[mi] = *(const bf16x8*)(
                    Asb + row * 64 + (((c2 * 4 + q16) ^ (row & 7)) << 3));
            }
            #pragma unroll
            for (int ni = 0; ni < 4; ni++) {
                const int row = wn + ni * 16 + l15;
                bfr[ni] = *(const bf16x8*)(
                    Bsb + row * 64 + (((c2 * 4 + q16) ^ (row & 7)) << 3));
            }
            #pragma unroll
            for (int mi = 0; mi < 4; mi++)
                #pragma unroll
                for (int ni = 0; ni < 4; ni++)
                    acc[mi][ni] = __builtin_amdgcn_mfma_f32_16x16x32_bf16(
                        af[mi], bfr[ni], acc[mi][ni], 0, 0, 0);
        }
        __syncthreads();
        cur ^= 1;
    }

    float bias_v[4];
    #pragma unroll
    for (int ni = 0; ni < 4; ni++)
        bias_v[ni] = bias[n0 + wn + ni * 16 + l15];

    #pragma unroll
    for (int mi = 0; mi < 4; mi++) {
        #pragma unroll
        for (int ni = 0; ni < 4; ni++) {
            const int n  = n0 + wn + ni * 16 + l15;
            const int h  = n >> 7;
            const int hd = n & (HD - 1);
            #pragma unroll
            for (int r = 0; r < 4; r++) {
                const int m = m0 + wm + mi * 16 + q16 * 4 + r;
                const int b = m >> 11;
                const int s = m & (SEQ - 1);
                const float val = acc[mi][ni][r] + bias_v[ni] * bscl;
                size_t idx;
                if (pz == 2)
                    idx = ((size_t)(b * NH + h) * HD + hd) * SEQ + s;
                else
                    idx = ((size_t)(b * NH + h) * SEQ + s) * HD + hd;
                dst[idx] = (bf16)val;
            }
        }
    }
}

// ---------------------------------------------------------------------------
// Kernel 2: flash attention.  ONE semantic change vs the verified round-7
// kernel: S orientation transposed via MFMA operand swap.
//   QK^T:  sf[nf] = mfma(kf, qf)  -> S[key][q], col = q = l15.
//   Each lane owns ONE query (16 of its 64 keys per tile):
//     - softmax: 15 in-lane fmax (v_max3) + 2 shfl_xor(16/32); ONE
//       alpha/exp2/m/l per lane (was 4 serial row-chains).
//     - mask: ONE u64 word per lane per tile (was 4 + variable shifts).
//   P written transposed into same Ps buffer (Pw[q=l15][key]) so pf/vf
//   reads and PV k-slot pairing are UNCHANGED; PV = mfma(vf, pf) -> O[d][q];
//   rescale uses lane's own alpha; epilogue indices remapped; l needs no
//   broadcast.  Staging, swizzles, geometry, setprio all frozen.
// ---------------------------------------------------------------------------
__global__ __launch_bounds__(256) void attn_kernel(
    const bf16* __restrict__ Q, const bf16* __restrict__ K,
    const bf16* __restrict__ Vt, const unsigned int* __restrict__ maskbits,
    float* __restrict__ out)
{
    __shared__ __align__(16) bf16 Ks[2][64 * 128];
    __shared__ __align__(16) bf16 Vs[2][128 * 64];
    __shared__ __align__(16) bf16 Ps[4][16 * 72];

    const int tid  = threadIdx.x;
    const int lane = tid & 63;
    const int w    = tid >> 6;
    const int q16  = lane >> 4;
    const int l15  = lane & 15;
    const int l3   = l15 & 7;

    const int b  = blockIdx.z;
    const int h  = blockIdx.y;
    const int q0 = blockIdx.x * 64;
    const int bh = b * NH + h;

    const bf16* Qb = Q  + (size_t)bh * SEQ * HD;
    const bf16* Kb = K  + (size_t)bh * SEQ * HD;
    const bf16* Vb = Vt + (size_t)bh * HD * SEQ;

    const int q_l = q0 + w * 16 + l15;           // this lane's query row
    const unsigned long long* mrowL =
        (const unsigned long long*)maskbits + (size_t)b * (SEQ * SEQ / 64)
        + (size_t)q_l * (SEQ / 64);

    bf16x8 qf[4];
    #pragma unroll
    for (int c = 0; c < 4; c++)
        qf[c] = *(const bf16x8*)(Qb + (size_t)q_l * HD + c * 32 + q16 * 8);

    f32x4 o[8] = {};
    float m_l = -__builtin_inff();
    float l_l = 0.f;

    const float MASKV = -1.0e6f * QSCL;

    auto stage = [&](int buf, int k0) {
        bf16* kd = &Ks[buf][0];
        bf16* vd = &Vs[buf][0];
        #pragma unroll
        for (int i = 0; i < 4; i++) {
            const int c   = i * 256 + tid;
            const int row = c >> 4;
            const int cir = c & 15;
            const bf16* src =
                Kb + (size_t)(k0 + row) * HD + ((cir ^ (row & 7)) << 3);
            __builtin_amdgcn_global_load_lds(
                (const AS1 void*)src,
                (AS3 void*)(kd + c * 8),
                16, 0, 0);
        }
        #pragma unroll
        for (int i = 0; i < 4; i++) {
            const int c   = i * 256 + tid;
            const int d   = c >> 3;
            const int cir = c & 7;
            const bf16* src =
                Vb + (size_t)d * SEQ + k0 + ((cir ^ (d & 7)) << 3);
            __builtin_amdgcn_global_load_lds(
                (const AS1 void*)src,
                (AS3 void*)(vd + c * 8),
                16, 0, 0);
        }
    };

    stage(0, 0);
    unsigned long long mwn = mrowL[0];
    __syncthreads();

    bf16* Pw = &Ps[w][0];
    int cur = 0;

    for (int kt = 0; kt < SEQ / 64; ++kt) {
        const unsigned long long mwv = mwn;

        if (kt + 1 < SEQ / 64) stage(cur ^ 1, (kt + 1) * 64);
        mwn = mrowL[(kt + 1) & (SEQ / 64 - 1)];

        const bf16* Ksb = &Ks[cur][0];
        const bf16* Vsb = &Vs[cur][0];

        // QK^T swapped: sf[nf][r] = S[key = kt*64 + nf*16 + q16*4 + r][q_l]
        f32x4 sf[4] = {};
        __builtin_amdgcn_s_setprio(1);
        #pragma unroll
        for (int c = 0; c < 4; c++) {
            #pragma unroll
            for (int nf = 0; nf < 4; nf++) {
                const bf16x8 kf = *(const bf16x8*)(
                    Ksb + (nf * 16 + l15) * 128 + (((c * 4 + q16) ^ l3) << 3));
                sf[nf] = __builtin_amdgcn_mfma_f32_16x16x32_bf16(
                    kf, qf[c], sf[nf], 0, 0, 0);
            }
        }
        __builtin_amdgcn_s_setprio(0);

        // mask: bit position of key within tile = nf*16 + q16*4 + r
        #pragma unroll
        for (int nf = 0; nf < 4; nf++)
            #pragma unroll
            for (int r = 0; r < 4; r++) {
                const int mk = (int)((mwv >> (nf * 16 + q16 * 4 + r)) & 1ull);
                sf[nf][r] = mk ? MASKV : sf[nf][r];
            }

        // per-lane softmax: in-lane max over 16 keys + 2 cross-group levels
        float t0 = fmaxf(fmaxf(sf[0][0], sf[0][1]), fmaxf(sf[0][2], sf[0][3]));
        float t1 = fmaxf(fmaxf(sf[1][0], sf[1][1]), fmaxf(sf[1][2], sf[1][3]));
        float t2 = fmaxf(fmaxf(sf[2][0], sf[2][1]), fmaxf(sf[2][2], sf[2][3]));
        float t3 = fmaxf(fmaxf(sf[3][0], sf[3][1]), fmaxf(sf[3][2], sf[3][3]));
        float mx = fmaxf(fmaxf(t0, t1), fmaxf(t2, t3));
        mx = fmaxf(mx, __shfl_xor(mx, 16));
        mx = fmaxf(mx, __shfl_xor(mx, 32));
        const float mnew  = fmaxf(m_l, mx);
        const float alpha = __builtin_amdgcn_exp2f(m_l - mnew);
        const bool  need  = mnew > m_l;
        m_l = mnew;

        float ps = 0.f;
        #pragma unroll
        for (int nf = 0; nf < 4; nf++)
            #pragma unroll
            for (int r = 0; r < 4; r++) {
                const float p = __builtin_amdgcn_exp2f(sf[nf][r] - mnew);
                sf[nf][r] = p;
                ps += p;
            }
        l_l = l_l * alpha + ps;   // per-lane partial (16 keys); merged at end

        if (__ballot(need)) {
            #pragma unroll
            for (int df = 0; df < 8; df++)
                #pragma unroll
                for (int r = 0; r < 4; r++)
                    o[df][r] *= alpha;
        }

        // P write transposed: Pw[q = l15][key = nf*16 + q16*4 + r]
        #pragma unroll
        for (int nf = 0; nf < 4; nf++)
            #pragma unroll
            for (int r = 0; r < 4; r++)
                Pw[l15 * 72 + nf * 16 + q16 * 4 + r] = (bf16)sf[nf][r];

        bf16x8 pf[2];
        #pragma unroll
        for (int cc = 0; cc < 2; cc++)
            pf[cc] = *(const bf16x8*)(Pw + l15 * 72 + cc * 32 + q16 * 8);

        // PV swapped: o[df] = O[d = df*16 + q16*4 + r][q_l]
        __builtin_amdgcn_s_setprio(1);
        #pragma unroll
        for (int df = 0; df < 8; df++) {
            #pragma unroll
            for (int cc = 0; cc < 2; cc++) {
                const bf16x8 vf = *(const bf16x8*)(
                    Vsb + (df * 16 + l15) * 64 + (((cc * 4 + q16) ^ l3) << 3));
                o[df] = __builtin_amdgcn_mfma_f32_16x16x32_bf16(
                    vf, pf[cc], o[df], 0, 0, 0);
            }
        }
        __builtin_amdgcn_s_setprio(0);

        __syncthreads();
        cur ^= 1;
    }

    // final l: merge the 4 per-group partials (replicated result in all lanes)
    float ls = l_l;
    ls += __shfl_xor(ls, 16);
    ls += __shfl_xor(ls, 32);
    const float linv = 1.0f / ls;

    #pragma unroll
    for (int df = 0; df < 8; df++) {
        #pragma unroll
        for (int r = 0; r < 4; r++) {
            out[((size_t)b * SEQ + q_l) * DM + h * HD + df * 16 + q16 * 4 + r] =
                o[df][r] * linv;
        }
    }
}

extern "C" void kernel_launch(void* const* d_in, const int* in_sizes, int n_in,
                              void* d_out, int out_size, void* d_ws, size_t ws_size,
                              hipStream_t stream) {
    const float* q    = (const float*)d_in[0];
    const float* k    = (const float*)d_in[1];
    const float* v    = (const float*)d_in[2];
    const void*  mask = d_in[3];
    const float* Wq   = (const float*)d_in[4];
    const float* bq   = (const float*)d_in[5];
    const float* Wk   = (const float*)d_in[6];
    const float* bk   = (const float*)d_in[7];
    const float* Wv   = (const float*)d_in[8];
    const float* bv   = (const float*)d_in[9];
    float* out = (float*)d_out;

    char* ws = (char*)d_ws;
    unsigned long long* bits = (unsigned long long*)ws;
    const size_t bits_bytes = (size_t)NB * SEQ * SEQ / 8;
    unsigned int* flag = (unsigned int*)(ws + bits_bytes);
    bf16* Qp = (bf16*)(ws + bits_bytes + 256);
    bf16* Kp = Qp + (size_t)NB * SEQ * DM;
    bf16* Vp = Kp + (size_t)NB * SEQ * DM;
    bf16* Xc = Vp + (size_t)NB * SEQ * DM;            // 24 MB
    bf16* Wt = Xc + (size_t)3 * NB * SEQ * DM;        //  6 MB

    // 3 launches: detect folded into prep (z==6), pack folded into proj (pz==3)
    prep_kernel<<<dim3(1024, 7), 256, 0, stream>>>(
        q, k, v, Wq, Wk, Wv, (const unsigned int*)mask, Xc, Wt, flag);

    dim3 pgrid(DM / 128, (NB * SEQ) / 128, 4);
    proj_kernel<<<pgrid, 256, 0, stream>>>(Xc, Wt, bq, bk, bv, Qp, Kp, Vp,
                                           mask, flag, bits);

    dim3 agrid(SEQ / 64, NH, NB);
    attn_kernel<<<agrid, 256, 0, stream>>>(Qp, Kp, Vp,
                                           (const unsigned int*)bits, out);
}

// Round 9
// 260.199 us; speedup vs baseline: 1.1735x; 1.0295x over previous
//
#include <hip/hip_runtime.h>

typedef __bf16 bf16;
typedef __attribute__((ext_vector_type(8))) __bf16 bf16x8;
typedef __attribute__((ext_vector_type(4))) __bf16 bf16x4;
typedef __attribute__((ext_vector_type(4))) float f32x4;
typedef __attribute__((ext_vector_type(4))) float fvec4;

#define NB 2
#define SEQ 2048
#define DM 1024
#define NH 8
#define HD 128

// scale folded into Wq/bq: 1/sqrt(HD) * log2(e)
#define QSCL (0.08838834764831845f * 1.4426950408889634f)

#define AS1 __attribute__((address_space(1)))
#define AS3 __attribute__((address_space(3)))

// ---------------------------------------------------------------------------
// Kernel 0: prep.  z<3: convert q/k/v fp32 -> bf16.  z in [3,5]: transpose-
// convert W -> Wt bf16 (QSCL folded into Wq).  z==6 (block 0 only): mask
// encoding detect -> flag.   (verified round-5 version, unchanged)
// ---------------------------------------------------------------------------
__global__ __launch_bounds__(256) void prep_kernel(
    const float* __restrict__ qi, const float* __restrict__ ki,
    const float* __restrict__ vi,
    const float* __restrict__ Wq, const float* __restrict__ Wk,
    const float* __restrict__ Wv,
    const unsigned int* __restrict__ mask32,
    bf16* __restrict__ Xc, bf16* __restrict__ Wt,
    unsigned int* __restrict__ flag)
{
    const int z   = blockIdx.y;
    const int tid = threadIdx.x;
    __shared__ __align__(16) bf16 tile[64][80];  // 80: keeps 16B-aligned rows
    __shared__ unsigned int sred[256];

    if (z < 3) {
        const float* src = (z == 0) ? qi : (z == 1) ? ki : vi;
        bf16* dst = Xc + (size_t)z * ((size_t)NB * SEQ * DM);
        const size_t base = (size_t)blockIdx.x * 4096 + (size_t)tid * 16;
        fvec4 f[4];
        #pragma unroll
        for (int j = 0; j < 4; j++)
            f[j] = *(const fvec4*)(src + base + j * 4);
        bf16x8 h0, h1;
        #pragma unroll
        for (int e = 0; e < 8; e++) {
            h0[e] = (bf16)f[e >> 2][e & 3];
            h1[e] = (bf16)f[2 + (e >> 2)][e & 3];
        }
        *(bf16x8*)(dst + base)     = h0;
        *(bf16x8*)(dst + base + 8) = h1;
    } else if (z < 6) {
        if (blockIdx.x >= 256) return;
        const float* W = (z == 3) ? Wq : (z == 4) ? Wk : Wv;
        bf16* dst = Wt + (size_t)(z - 3) * ((size_t)DM * DM);
        const float scl = (z == 3) ? QSCL : 1.0f;
        const int n0 = (blockIdx.x & 15) * 64;
        const int k0 = (blockIdx.x >> 4) * 64;
        #pragma unroll
        for (int p = 0; p < 4; p++) {
            const int r = p * 16 + (tid >> 4);      // k row
            const int c = (tid & 15) * 4;           // n col
            const fvec4 wv = *(const fvec4*)(W + (size_t)(k0 + r) * DM + n0 + c);
            #pragma unroll
            for (int j = 0; j < 4; j++)
                tile[c + j][r] = (bf16)(wv[j] * scl);
        }
        __syncthreads();
        #pragma unroll
        for (int p = 0; p < 2; p++) {
            const int row = p * 32 + (tid >> 3);    // n row of output
            const int ch  = tid & 7;                // 8-elem k chunk
            const bf16x8 hv = *(const bf16x8*)(&tile[row][ch * 8]);
            *(bf16x8*)(dst + (size_t)(n0 + row) * DM + k0 + ch * 8) = hv;
        }
    } else {
        // mask encoding detect (byte-bool vs 32-bit-word bool), 1 block
        if (blockIdx.x != 0) return;
        unsigned int f = 0;
        for (int i = tid; i < 1024; i += 256) {
            const unsigned int w2 = mask32[i];
            if ((w2 & 0xFEFEFEFEu) == 0u && (w2 & 0xFFFFFF00u) != 0u) f = 1;
        }
        sred[tid] = f;
        __syncthreads();
        if (tid == 0) {
            unsigned int r = 0;
            for (int i = 0; i < 256; i++) r |= sred[i];
            *flag = r;
        }
    }
}

// ---------------------------------------------------------------------------
// Kernel 1: projection GEMM + vectorized mask pack.  ONE change vs round 8:
// the V store (pz==2) permutes the key index within each 64-key tile by
// sigma^-1 (key 16nf+4g+r -> slot (nf>>1)*32 + g*8 + (nf&1)*4 + r), so that
// attn's PV B-fragment slot ordering matches the per-lane P register layout
// -> attn's P LDS round-trip becomes a pure register repack.
// (s does not vary with l15, so store coalescing is unchanged.)
// ---------------------------------------------------------------------------
__global__ __launch_bounds__(256) void proj_kernel(
    const bf16* __restrict__ Xc, const bf16* __restrict__ Wt,
    const float* __restrict__ bq, const float* __restrict__ bk,
    const float* __restrict__ bv,
    bf16* __restrict__ Qo, bf16* __restrict__ Ko, bf16* __restrict__ Vto,
    const void* __restrict__ mask, const unsigned int* __restrict__ flag,
    unsigned long long* __restrict__ bits)
{
    __shared__ __align__(16) bf16 As[2][128 * 64];
    __shared__ __align__(16) bf16 Bs[2][128 * 64];

    const int pz = blockIdx.z;
    const int tid = threadIdx.x;

    if (pz == 3) {
        // ---- mask pack: 256 blocks x 256 threads x 8 iters x 16 elems ----
        const bool bytem = (*flag & 1u) != 0;
        const int wid = blockIdx.y * 8 + blockIdx.x;        // 0..255
        const int t   = wid * 256 + tid;                    // 0..65535
        unsigned short* const bits16o = (unsigned short*)bits;
        #pragma unroll 2
        for (int it = 0; it < 8; ++it) {
            const size_t e0 = ((size_t)it * 65536 + t) * 16;  // element base
            unsigned int b16 = 0;
            if (bytem) {
                const uint4 wv = *(const uint4*)((const unsigned char*)mask + e0);
                const unsigned int wd[4] = {wv.x, wv.y, wv.z, wv.w};
                #pragma unroll
                for (int j = 0; j < 4; j++) {
                    b16 |= ((wd[j] & 0x000000FFu) ? 1u : 0u) << (4 * j + 0);
                    b16 |= ((wd[j] & 0x0000FF00u) ? 1u : 0u) << (4 * j + 1);
                    b16 |= ((wd[j] & 0x00FF0000u) ? 1u : 0u) << (4 * j + 2);
                    b16 |= ((wd[j] & 0xFF000000u) ? 1u : 0u) << (4 * j + 3);
                }
            } else {
                const unsigned int* mw = (const unsigned int*)mask + e0;
                #pragma unroll
                for (int j = 0; j < 4; j++) {
                    const uint4 wv = *(const uint4*)(mw + 4 * j);
                    b16 |= (wv.x ? 1u : 0u) << (4 * j + 0);
                    b16 |= (wv.y ? 1u : 0u) << (4 * j + 1);
                    b16 |= (wv.z ? 1u : 0u) << (4 * j + 2);
                    b16 |= (wv.w ? 1u : 0u) << (4 * j + 3);
                }
            }
            bits16o[e0 >> 4] = (unsigned short)b16;
        }
        return;
    }

    const bf16* X  = Xc + (size_t)pz * ((size_t)NB * SEQ * DM);
    const bf16* Bt = Wt + (size_t)pz * ((size_t)DM * DM);
    const float* bias = (pz == 0) ? bq : (pz == 1) ? bk : bv;
    const float bscl  = (pz == 0) ? QSCL : 1.0f;
    bf16* dst = (pz == 0) ? Qo : (pz == 1) ? Ko : Vto;

    const int lane = tid & 63;
    const int w    = tid >> 6;
    const int q16  = lane >> 4;
    const int l15  = lane & 15;

    const int m0 = blockIdx.y * 128;
    const int n0 = blockIdx.x * 128;
    const int wm = (w >> 1) * 64;
    const int wn = (w & 1) * 64;

    auto stage = [&](int buf, int k0) {
        #pragma unroll
        for (int i = 0; i < 4; i++) {
            const int c   = i * 256 + tid;
            const int row = c >> 3;
            const int cir = c & 7;
            const bf16* src =
                X + (size_t)(m0 + row) * DM + k0 + ((cir ^ (row & 7)) << 3);
            __builtin_amdgcn_global_load_lds(
                (const AS1 void*)src,
                (AS3 void*)(&As[buf][c * 8]),
                16, 0, 0);
        }
        #pragma unroll
        for (int i = 0; i < 4; i++) {
            const int c   = i * 256 + tid;
            const int row = c >> 3;
            const int cir = c & 7;
            const bf16* src =
                Bt + (size_t)(n0 + row) * DM + k0 + ((cir ^ (row & 7)) << 3);
            __builtin_amdgcn_global_load_lds(
                (const AS1 void*)src,
                (AS3 void*)(&Bs[buf][c * 8]),
                16, 0, 0);
        }
    };

    f32x4 acc[4][4] = {};
    stage(0, 0);
    __syncthreads();
    int cur = 0;

    for (int kt = 0; kt < DM / 64; ++kt) {
        if (kt + 1 < DM / 64) stage(cur ^ 1, (kt + 1) * 64);
        const bf16* Asb = &As[cur][0];
        const bf16* Bsb = &Bs[cur][0];
        #pragma unroll
        for (int c2 = 0; c2 < 2; c2++) {
            bf16x8 af[4], bfr[4];
            #pragma unroll
            for (int mi = 0; mi < 4; mi++) {
                const int row = wm + mi * 16 + l15;
                af[mi] = *(const bf16x8*)(
                    Asb + row * 64 + (((c2 * 4 + q16) ^ (row & 7)) << 3));
            }
            #pragma unroll
            for (int ni = 0; ni < 4; ni++) {
                const int row = wn + ni * 16 + l15;
                bfr[ni] = *(const bf16x8*)(
                    Bsb + row * 64 + (((c2 * 4 + q16) ^ (row & 7)) << 3));
            }
            #pragma unroll
            for (int mi = 0; mi < 4; mi++)
                #pragma unroll
                for (int ni = 0; ni < 4; ni++)
                    acc[mi][ni] = __builtin_amdgcn_mfma_f32_16x16x32_bf16(
                        af[mi], bfr[ni], acc[mi][ni], 0, 0, 0);
        }
        __syncthreads();
        cur ^= 1;
    }

    float bias_v[4];
    #pragma unroll
    for (int ni = 0; ni < 4; ni++)
        bias_v[ni] = bias[n0 + wn + ni * 16 + l15];

    #pragma unroll
    for (int mi = 0; mi < 4; mi++) {
        #pragma unroll
        for (int ni = 0; ni < 4; ni++) {
            const int n  = n0 + wn + ni * 16 + l15;
            const int h  = n >> 7;
            const int hd = n & (HD - 1);
            #pragma unroll
            for (int r = 0; r < 4; r++) {
                const int m = m0 + wm + mi * 16 + q16 * 4 + r;
                const int b = m >> 11;
                const int s = m & (SEQ - 1);
                const float val = acc[mi][ni][r] + bias_v[ni] * bscl;
                size_t idx;
                if (pz == 2) {
                    // sigma^-1 key permute within each 64-key tile:
                    // key 16nf+4g+rr -> slot (nf>>1)*32 + g*8 + (nf&1)*4 + rr
                    const int s63 = s & 63;
                    const int nf  = s63 >> 4;
                    const int g   = (s63 >> 2) & 3;
                    const int rr  = s63 & 3;
                    const int slot = (nf >> 1) * 32 + g * 8 + (nf & 1) * 4 + rr;
                    const int sp = (s & ~63) | slot;
                    idx = ((size_t)(b * NH + h) * HD + hd) * SEQ + sp;
                } else {
                    idx = ((size_t)(b * NH + h) * SEQ + s) * HD + hd;
                }
                dst[idx] = (bf16)val;
            }
        }
    }
}

// ---------------------------------------------------------------------------
// Kernel 2: flash attention.  ONE semantic change vs the verified round-8
// kernel: the P LDS round-trip is GONE.  V's key axis is sigma-permuted at
// the proj store (slot cc*32+q16*8+j holds key (2cc+(j>>2))*16+4*q16+(j&3)),
// which makes the PV B-fragment exactly the lane's own softmax registers:
//   pf[cc] = { sf[2cc][0..3], sf[2cc+1][0..3] }   (pure register repack).
// Vs read pattern, Ks/mask ordering, softmax, staging, swizzles, geometry,
// setprio all unchanged.  Ps buffer deleted (LDS 74752 -> 65536).
// ---------------------------------------------------------------------------
__global__ __launch_bounds__(256) void attn_kernel(
    const bf16* __restrict__ Q, const bf16* __restrict__ K,
    const bf16* __restrict__ Vt, const unsigned int* __restrict__ maskbits,
    float* __restrict__ out)
{
    __shared__ __align__(16) bf16 Ks[2][64 * 128];
    __shared__ __align__(16) bf16 Vs[2][128 * 64];

    const int tid  = threadIdx.x;
    const int lane = tid & 63;
    const int w    = tid >> 6;
    const int q16  = lane >> 4;
    const int l15  = lane & 15;
    const int l3   = l15 & 7;

    const int b  = blockIdx.z;
    const int h  = blockIdx.y;
    const int q0 = blockIdx.x * 64;
    const int bh = b * NH + h;

    const bf16* Qb = Q  + (size_t)bh * SEQ * HD;
    const bf16* Kb = K  + (size_t)bh * SEQ * HD;
    const bf16* Vb = Vt + (size_t)bh * HD * SEQ;

    const int q_l = q0 + w * 16 + l15;           // this lane's query row
    const unsigned long long* mrowL =
        (const unsigned long long*)maskbits + (size_t)b * (SEQ * SEQ / 64)
        + (size_t)q_l * (SEQ / 64);

    bf16x8 qf[4];
    #pragma unroll
    for (int c = 0; c < 4; c++)
        qf[c] = *(const bf16x8*)(Qb + (size_t)q_l * HD + c * 32 + q16 * 8);

    f32x4 o[8] = {};
    float m_l = -__builtin_inff();
    float l_l = 0.f;

    const float MASKV = -1.0e6f * QSCL;

    auto stage = [&](int buf, int k0) {
        bf16* kd = &Ks[buf][0];
        bf16* vd = &Vs[buf][0];
        #pragma unroll
        for (int i = 0; i < 4; i++) {
            const int c   = i * 256 + tid;
            const int row = c >> 4;
            const int cir = c & 15;
            const bf16* src =
                Kb + (size_t)(k0 + row) * HD + ((cir ^ (row & 7)) << 3);
            __builtin_amdgcn_global_load_lds(
                (const AS1 void*)src,
                (AS3 void*)(kd + c * 8),
                16, 0, 0);
        }
        #pragma unroll
        for (int i = 0; i < 4; i++) {
            const int c   = i * 256 + tid;
            const int d   = c >> 3;
            const int cir = c & 7;
            const bf16* src =
                Vb + (size_t)d * SEQ + k0 + ((cir ^ (d & 7)) << 3);
            __builtin_amdgcn_global_load_lds(
                (const AS1 void*)src,
                (AS3 void*)(vd + c * 8),
                16, 0, 0);
        }
    };

    stage(0, 0);
    unsigned long long mwn = mrowL[0];
    __syncthreads();

    int cur = 0;

    for (int kt = 0; kt < SEQ / 64; ++kt) {
        const unsigned long long mwv = mwn;

        if (kt + 1 < SEQ / 64) stage(cur ^ 1, (kt + 1) * 64);
        mwn = mrowL[(kt + 1) & (SEQ / 64 - 1)];

        const bf16* Ksb = &Ks[cur][0];
        const bf16* Vsb = &Vs[cur][0];

        // QK^T swapped: sf[nf][r] = S[key = kt*64 + nf*16 + q16*4 + r][q_l]
        f32x4 sf[4] = {};
        __builtin_amdgcn_s_setprio(1);
        #pragma unroll
        for (int c = 0; c < 4; c++) {
            #pragma unroll
            for (int nf = 0; nf < 4; nf++) {
                const bf16x8 kf = *(const bf16x8*)(
                    Ksb + (nf * 16 + l15) * 128 + (((c * 4 + q16) ^ l3) << 3));
                sf[nf] = __builtin_amdgcn_mfma_f32_16x16x32_bf16(
                    kf, qf[c], sf[nf], 0, 0, 0);
            }
        }
        __builtin_amdgcn_s_setprio(0);

        // mask: bit position of key within tile = nf*16 + q16*4 + r
        #pragma unroll
        for (int nf = 0; nf < 4; nf++)
            #pragma unroll
            for (int r = 0; r < 4; r++) {
                const int mk = (int)((mwv >> (nf * 16 + q16 * 4 + r)) & 1ull);
                sf[nf][r] = mk ? MASKV : sf[nf][r];
            }

        // per-lane softmax: in-lane max over 16 keys + 2 cross-group levels
        float t0 = fmaxf(fmaxf(sf[0][0], sf[0][1]), fmaxf(sf[0][2], sf[0][3]));
        float t1 = fmaxf(fmaxf(sf[1][0], sf[1][1]), fmaxf(sf[1][2], sf[1][3]));
        float t2 = fmaxf(fmaxf(sf[2][0], sf[2][1]), fmaxf(sf[2][2], sf[2][3]));
        float t3 = fmaxf(fmaxf(sf[3][0], sf[3][1]), fmaxf(sf[3][2], sf[3][3]));
        float mx = fmaxf(fmaxf(t0, t1), fmaxf(t2, t3));
        mx = fmaxf(mx, __shfl_xor(mx, 16));
        mx = fmaxf(mx, __shfl_xor(mx, 32));
        const float mnew  = fmaxf(m_l, mx);
        const float alpha = __builtin_amdgcn_exp2f(m_l - mnew);
        const bool  need  = mnew > m_l;
        m_l = mnew;

        float ps = 0.f;
        #pragma unroll
        for (int nf = 0; nf < 4; nf++)
            #pragma unroll
            for (int r = 0; r < 4; r++) {
                const float p = __builtin_amdgcn_exp2f(sf[nf][r] - mnew);
                sf[nf][r] = p;
                ps += p;
            }
        l_l = l_l * alpha + ps;   // per-lane partial (16 keys); merged at end

        if (__ballot(need)) {
            #pragma unroll
            for (int df = 0; df < 8; df++)
                #pragma unroll
                for (int r = 0; r < 4; r++)
                    o[df][r] *= alpha;
        }

        // P -> PV B-fragments: PURE register repack (sigma-permuted V).
        // slot (cc, q16, j) holds key (2cc+(j>>2))*16 + 4*q16 + (j&3)
        //   => pf[cc][j] = sf[2cc + (j>>2)][j&3]
        bf16x8 pf[2];
        #pragma unroll
        for (int cc = 0; cc < 2; cc++) {
            bf16x8 t;
            #pragma unroll
            for (int j = 0; j < 8; j++)
                t[j] = (bf16)sf[2 * cc + (j >> 2)][j & 3];
            pf[cc] = t;
        }

        // PV swapped: o[df] = O[d = df*16 + q16*4 + r][q_l]
        __builtin_amdgcn_s_setprio(1);
        #pragma unroll
        for (int df = 0; df < 8; df++) {
            #pragma unroll
            for (int cc = 0; cc < 2; cc++) {
                const bf16x8 vf = *(const bf16x8*)(
                    Vsb + (df * 16 + l15) * 64 + (((cc * 4 + q16) ^ l3) << 3));
                o[df] = __builtin_amdgcn_mfma_f32_16x16x32_bf16(
                    vf, pf[cc], o[df], 0, 0, 0);
            }
        }
        __builtin_amdgcn_s_setprio(0);

        __syncthreads();
        cur ^= 1;
    }

    // final l: merge the 4 per-group partials (replicated result in all lanes)
    float ls = l_l;
    ls += __shfl_xor(ls, 16);
    ls += __shfl_xor(ls, 32);
    const float linv = 1.0f / ls;

    #pragma unroll
    for (int df = 0; df < 8; df++) {
        #pragma unroll
        for (int r = 0; r < 4; r++) {
            out[((size_t)b * SEQ + q_l) * DM + h * HD + df * 16 + q16 * 4 + r] =
                o[df][r] * linv;
        }
    }
}

extern "C" void kernel_launch(void* const* d_in, const int* in_sizes, int n_in,
                              void* d_out, int out_size, void* d_ws, size_t ws_size,
                              hipStream_t stream) {
    const float* q    = (const float*)d_in[0];
    const float* k    = (const float*)d_in[1];
    const float* v    = (const float*)d_in[2];
    const void*  mask = d_in[3];
    const float* Wq   = (const float*)d_in[4];
    const float* bq   = (const float*)d_in[5];
    const float* Wk   = (const float*)d_in[6];
    const float* bk   = (const float*)d_in[7];
    const float* Wv   = (const float*)d_in[8];
    const float* bv   = (const float*)d_in[9];
    float* out = (float*)d_out;

    char* ws = (char*)d_ws;
    unsigned long long* bits = (unsigned long long*)ws;
    const size_t bits_bytes = (size_t)NB * SEQ * SEQ / 8;
    unsigned int* flag = (unsigned int*)(ws + bits_bytes);
    bf16* Qp = (bf16*)(ws + bits_bytes + 256);
    bf16* Kp = Qp + (size_t)NB * SEQ * DM;
    bf16* Vp = Kp + (size_t)NB * SEQ * DM;
    bf16* Xc = Vp + (size_t)NB * SEQ * DM;            // 24 MB
    bf16* Wt = Xc + (size_t)3 * NB * SEQ * DM;        //  6 MB

    // 3 launches: detect folded into prep (z==6), pack folded into proj (pz==3)
    prep_kernel<<<dim3(1024, 7), 256, 0, stream>>>(
        q, k, v, Wq, Wk, Wv, (const unsigned int*)mask, Xc, Wt, flag);

    dim3 pgrid(DM / 128, (NB * SEQ) / 128, 4);
    proj_kernel<<<pgrid, 256, 0, stream>>>(Xc, Wt, bq, bk, bv, Qp, Kp, Vp,
                                           mask, flag, bits);

    dim3 agrid(SEQ / 64, NH, NB);
    attn_kernel<<<agrid, 256, 0, stream>>>(Qp, Kp, Vp,
                                           (const unsigned int*)bits, out);
}

// Round 10
// 248.529 us; speedup vs baseline: 1.2286x; 1.0470x over previous
//
#include <hip/hip_runtime.h>

typedef __bf16 bf16;
typedef __attribute__((ext_vector_type(8))) __bf16 bf16x8;
typedef __attribute__((ext_vector_type(4))) __bf16 bf16x4;
typedef __attribute__((ext_vector_type(4))) float f32x4;
typedef __attribute__((ext_vector_type(4))) float fvec4;

#define NB 2
#define SEQ 2048
#define DM 1024
#define NH 8
#define HD 128

// scale folded into Wq/bq: 1/sqrt(HD) * log2(e)
#define QSCL (0.08838834764831845f * 1.4426950408889634f)

#define AS1 __attribute__((address_space(1)))
#define AS3 __attribute__((address_space(3)))

// ---------------------------------------------------------------------------
// Kernel 0: prep.  z<3: convert q/k/v fp32 -> bf16.  z in [3,5]: transpose-
// convert W -> Wt bf16 (QSCL folded into Wq).  z==6 (block 0 only): mask
// encoding detect -> flag.   (verified round-5 version, unchanged)
// ---------------------------------------------------------------------------
__global__ __launch_bounds__(256) void prep_kernel(
    const float* __restrict__ qi, const float* __restrict__ ki,
    const float* __restrict__ vi,
    const float* __restrict__ Wq, const float* __restrict__ Wk,
    const float* __restrict__ Wv,
    const unsigned int* __restrict__ mask32,
    bf16* __restrict__ Xc, bf16* __restrict__ Wt,
    unsigned int* __restrict__ flag)
{
    const int z   = blockIdx.y;
    const int tid = threadIdx.x;
    __shared__ __align__(16) bf16 tile[64][80];  // 80: keeps 16B-aligned rows
    __shared__ unsigned int sred[256];

    if (z < 3) {
        const float* src = (z == 0) ? qi : (z == 1) ? ki : vi;
        bf16* dst = Xc + (size_t)z * ((size_t)NB * SEQ * DM);
        const size_t base = (size_t)blockIdx.x * 4096 + (size_t)tid * 16;
        fvec4 f[4];
        #pragma unroll
        for (int j = 0; j < 4; j++)
            f[j] = *(const fvec4*)(src + base + j * 4);
        bf16x8 h0, h1;
        #pragma unroll
        for (int e = 0; e < 8; e++) {
            h0[e] = (bf16)f[e >> 2][e & 3];
            h1[e] = (bf16)f[2 + (e >> 2)][e & 3];
        }
        *(bf16x8*)(dst + base)     = h0;
        *(bf16x8*)(dst + base + 8) = h1;
    } else if (z < 6) {
        if (blockIdx.x >= 256) return;
        const float* W = (z == 3) ? Wq : (z == 4) ? Wk : Wv;
        bf16* dst = Wt + (size_t)(z - 3) * ((size_t)DM * DM);
        const float scl = (z == 3) ? QSCL : 1.0f;
        const int n0 = (blockIdx.x & 15) * 64;
        const int k0 = (blockIdx.x >> 4) * 64;
        #pragma unroll
        for (int p = 0; p < 4; p++) {
            const int r = p * 16 + (tid >> 4);      // k row
            const int c = (tid & 15) * 4;           // n col
            const fvec4 wv = *(const fvec4*)(W + (size_t)(k0 + r) * DM + n0 + c);
            #pragma unroll
            for (int j = 0; j < 4; j++)
                tile[c + j][r] = (bf16)(wv[j] * scl);
        }
        __syncthreads();
        #pragma unroll
        for (int p = 0; p < 2; p++) {
            const int row = p * 32 + (tid >> 3);    // n row of output
            const int ch  = tid & 7;                // 8-elem k chunk
            const bf16x8 hv = *(const bf16x8*)(&tile[row][ch * 8]);
            *(bf16x8*)(dst + (size_t)(n0 + row) * DM + k0 + ch * 8) = hv;
        }
    } else {
        // mask encoding detect (byte-bool vs 32-bit-word bool), 1 block
        if (blockIdx.x != 0) return;
        unsigned int f = 0;
        for (int i = tid; i < 1024; i += 256) {
            const unsigned int w2 = mask32[i];
            if ((w2 & 0xFEFEFEFEu) == 0u && (w2 & 0xFFFFFF00u) != 0u) f = 1;
        }
        sred[tid] = f;
        __syncthreads();
        if (tid == 0) {
            unsigned int r = 0;
            for (int i = 0; i < 256; i++) r |= sred[i];
            *flag = r;
        }
    }
}

// ---------------------------------------------------------------------------
// Kernel 1: projection GEMM + vectorized mask pack.  ONE change vs round 9:
// XCD-aware block swizzle (T1) for the GEMM slices.  Consecutive linear
// block ids (= round-robin XCDs) previously shared the same X panel ->
// every XCD re-fetched it from HBM (FETCH 117.8 MB vs ~40 ideal).  The
// bijective 8x32 transpose nlid=(lid&7)*32+(lid>>3) gives each XCD 4
// m-panels x all 8 n-panels: 1 MB X + 2 MB Wt < 4 MB L2.
// ---------------------------------------------------------------------------
__global__ __launch_bounds__(256) void proj_kernel(
    const bf16* __restrict__ Xc, const bf16* __restrict__ Wt,
    const float* __restrict__ bq, const float* __restrict__ bk,
    const float* __restrict__ bv,
    bf16* __restrict__ Qo, bf16* __restrict__ Ko, bf16* __restrict__ Vto,
    const void* __restrict__ mask, const unsigned int* __restrict__ flag,
    unsigned long long* __restrict__ bits)
{
    __shared__ __align__(16) bf16 As[2][128 * 64];
    __shared__ __align__(16) bf16 Bs[2][128 * 64];

    const int pz = blockIdx.z;
    const int tid = threadIdx.x;

    if (pz == 3) {
        // ---- mask pack: 256 blocks x 256 threads x 8 iters x 16 elems ----
        const bool bytem = (*flag & 1u) != 0;
        const int wid = blockIdx.y * 8 + blockIdx.x;        // 0..255
        const int t   = wid * 256 + tid;                    // 0..65535
        unsigned short* const bits16o = (unsigned short*)bits;
        #pragma unroll 2
        for (int it = 0; it < 8; ++it) {
            const size_t e0 = ((size_t)it * 65536 + t) * 16;  // element base
            unsigned int b16 = 0;
            if (bytem) {
                const uint4 wv = *(const uint4*)((const unsigned char*)mask + e0);
                const unsigned int wd[4] = {wv.x, wv.y, wv.z, wv.w};
                #pragma unroll
                for (int j = 0; j < 4; j++) {
                    b16 |= ((wd[j] & 0x000000FFu) ? 1u : 0u) << (4 * j + 0);
                    b16 |= ((wd[j] & 0x0000FF00u) ? 1u : 0u) << (4 * j + 1);
                    b16 |= ((wd[j] & 0x00FF0000u) ? 1u : 0u) << (4 * j + 2);
                    b16 |= ((wd[j] & 0xFF000000u) ? 1u : 0u) << (4 * j + 3);
                }
            } else {
                const unsigned int* mw = (const unsigned int*)mask + e0;
                #pragma unroll
                for (int j = 0; j < 4; j++) {
                    const uint4 wv = *(const uint4*)(mw + 4 * j);
                    b16 |= (wv.x ? 1u : 0u) << (4 * j + 0);
                    b16 |= (wv.y ? 1u : 0u) << (4 * j + 1);
                    b16 |= (wv.z ? 1u : 0u) << (4 * j + 2);
                    b16 |= (wv.w ? 1u : 0u) << (4 * j + 3);
                }
            }
            bits16o[e0 >> 4] = (unsigned short)b16;
        }
        return;
    }

    const bf16* X  = Xc + (size_t)pz * ((size_t)NB * SEQ * DM);
    const bf16* Bt = Wt + (size_t)pz * ((size_t)DM * DM);
    const float* bias = (pz == 0) ? bq : (pz == 1) ? bk : bv;
    const float bscl  = (pz == 0) ? QSCL : 1.0f;
    bf16* dst = (pz == 0) ? Qo : (pz == 1) ? Ko : Vto;

    const int lane = tid & 63;
    const int w    = tid >> 6;
    const int q16  = lane >> 4;
    const int l15  = lane & 15;

    // T1 XCD swizzle: bijective 8x32 transpose of the per-pz block map.
    const int lid  = (int)blockIdx.x + 8 * (int)blockIdx.y;   // 0..255
    const int nlid = (lid & 7) * 32 + (lid >> 3);
    const int m0 = (nlid >> 3) * 128;
    const int n0 = (nlid & 7) * 128;
    const int wm = (w >> 1) * 64;
    const int wn = (w & 1) * 64;

    auto stage = [&](int buf, int k0) {
        #pragma unroll
        for (int i = 0; i < 4; i++) {
            const int c   = i * 256 + tid;
            const int row = c >> 3;
            const int cir = c & 7;
            const bf16* src =
                X + (size_t)(m0 + row) * DM + k0 + ((cir ^ (row & 7)) << 3);
            __builtin_amdgcn_global_load_lds(
                (const AS1 void*)src,
                (AS3 void*)(&As[buf][c * 8]),
                16, 0, 0);
        }
        #pragma unroll
        for (int i = 0; i < 4; i++) {
            const int c   = i * 256 + tid;
            const int row = c >> 3;
            const int cir = c & 7;
            const bf16* src =
                Bt + (size_t)(n0 + row) * DM + k0 + ((cir ^ (row & 7)) << 3);
            __builtin_amdgcn_global_load_lds(
                (const AS1 void*)src,
                (AS3 void*)(&Bs[buf][c * 8]),
                16, 0, 0);
        }
    };

    f32x4 acc[4][4] = {};
    stage(0, 0);
    __syncthreads();
    int cur = 0;

    for (int kt = 0; kt < DM / 64; ++kt) {
        if (kt + 1 < DM / 64) stage(cur ^ 1, (kt + 1) * 64);
        const bf16* Asb = &As[cur][0];
        const bf16* Bsb = &Bs[cur][0];
        #pragma unroll
        for (int c2 = 0; c2 < 2; c2++) {
            bf16x8 af[4], bfr[4];
            #pragma unroll
            for (int mi = 0; mi < 4; mi++) {
                const int row = wm + mi * 16 + l15;
                af[mi] = *(const bf16x8*)(
                    Asb + row * 64 + (((c2 * 4 + q16) ^ (row & 7)) << 3));
            }
            #pragma unroll
            for (int ni = 0; ni < 4; ni++) {
                const int row = wn + ni * 16 + l15;
                bfr[ni] = *(const bf16x8*)(
                    Bsb + row * 64 + (((c2 * 4 + q16) ^ (row & 7)) << 3));
            }
            #pragma unroll
            for (int mi = 0; mi < 4; mi++)
                #pragma unroll
                for (int ni = 0; ni < 4; ni++)
                    acc[mi][ni] = __builtin_amdgcn_mfma_f32_16x16x32_bf16(
                        af[mi], bfr[ni], acc[mi][ni], 0, 0, 0);
        }
        __syncthreads();
        cur ^= 1;
    }

    float bias_v[4];
    #pragma unroll
    for (int ni = 0; ni < 4; ni++)
        bias_v[ni] = bias[n0 + wn + ni * 16 + l15];

    #pragma unroll
    for (int mi = 0; mi < 4; mi++) {
        #pragma unroll
        for (int ni = 0; ni < 4; ni++) {
            const int n  = n0 + wn + ni * 16 + l15;
            const int h  = n >> 7;
            const int hd = n & (HD - 1);
            #pragma unroll
            for (int r = 0; r < 4; r++) {
                const int m = m0 + wm + mi * 16 + q16 * 4 + r;
                const int b = m >> 11;
                const int s = m & (SEQ - 1);
                const float val = acc[mi][ni][r] + bias_v[ni] * bscl;
                size_t idx;
                if (pz == 2) {
                    // sigma^-1 key permute within each 64-key tile:
                    // key 16nf+4g+rr -> slot (nf>>1)*32 + g*8 + (nf&1)*4 + rr
                    const int s63 = s & 63;
                    const int nf  = s63 >> 4;
                    const int g   = (s63 >> 2) & 3;
                    const int rr  = s63 & 3;
                    const int slot = (nf >> 1) * 32 + g * 8 + (nf & 1) * 4 + rr;
                    const int sp = (s & ~63) | slot;
                    idx = ((size_t)(b * NH + h) * HD + hd) * SEQ + sp;
                } else {
                    idx = ((size_t)(b * NH + h) * SEQ + s) * HD + hd;
                }
                dst[idx] = (bf16)val;
            }
        }
    }
}

// ---------------------------------------------------------------------------
// Kernel 2: flash attention.  ONE change vs the verified round-9 kernel:
// XCD-aware block swizzle (T1).  The 32 q-tile blocks of one (b,h) share
// 1 MB of K+V and 4.2 MB of mask bits (bits are per-b, shared by all 8
// heads!) but previously round-robined over 8 XCDs.  Bijective 8x64
// transpose nlid=(lid&7)*64+(lid>>3) puts bh in {2c, 2c+1} (same b) on
// XCD c -> K/V and bits become L2-local.  All math bit-identical.
// ---------------------------------------------------------------------------
__global__ __launch_bounds__(256) void attn_kernel(
    const bf16* __restrict__ Q, const bf16* __restrict__ K,
    const bf16* __restrict__ Vt, const unsigned int* __restrict__ maskbits,
    float* __restrict__ out)
{
    __shared__ __align__(16) bf16 Ks[2][64 * 128];
    __shared__ __align__(16) bf16 Vs[2][128 * 64];

    const int tid  = threadIdx.x;
    const int lane = tid & 63;
    const int w    = tid >> 6;
    const int q16  = lane >> 4;
    const int l15  = lane & 15;
    const int l3   = l15 & 7;

    // T1 XCD swizzle: bijective 8x64 transpose of the 512-block map.
    const int lid  = (int)blockIdx.x
                   + 32 * ((int)blockIdx.y + 8 * (int)blockIdx.z);
    const int nlid = (lid & 7) * 64 + (lid >> 3);
    const int q0  = (nlid & 31) * 64;
    const int bh  = nlid >> 5;          // 0..15 == b*NH + h
    const int b   = bh >> 3;
    const int h   = bh & 7;

    const bf16* Qb = Q  + (size_t)bh * SEQ * HD;
    const bf16* Kb = K  + (size_t)bh * SEQ * HD;
    const bf16* Vb = Vt + (size_t)bh * HD * SEQ;

    const int q_l = q0 + w * 16 + l15;           // this lane's query row
    const unsigned long long* mrowL =
        (const unsigned long long*)maskbits + (size_t)b * (SEQ * SEQ / 64)
        + (size_t)q_l * (SEQ / 64);

    bf16x8 qf[4];
    #pragma unroll
    for (int c = 0; c < 4; c++)
        qf[c] = *(const bf16x8*)(Qb + (size_t)q_l * HD + c * 32 + q16 * 8);

    f32x4 o[8] = {};
    float m_l = -__builtin_inff();
    float l_l = 0.f;

    const float MASKV = -1.0e6f * QSCL;

    auto stage = [&](int buf, int k0) {
        bf16* kd = &Ks[buf][0];
        bf16* vd = &Vs[buf][0];
        #pragma unroll
        for (int i = 0; i < 4; i++) {
            const int c   = i * 256 + tid;
            const int row = c >> 4;
            const int cir = c & 15;
            const bf16* src =
                Kb + (size_t)(k0 + row) * HD + ((cir ^ (row & 7)) << 3);
            __builtin_amdgcn_global_load_lds(
                (const AS1 void*)src,
                (AS3 void*)(kd + c * 8),
                16, 0, 0);
        }
        #pragma unroll
        for (int i = 0; i < 4; i++) {
            const int c   = i * 256 + tid;
            const int d   = c >> 3;
            const int cir = c & 7;
            const bf16* src =
                Vb + (size_t)d * SEQ + k0 + ((cir ^ (d & 7)) << 3);
            __builtin_amdgcn_global_load_lds(
                (const AS1 void*)src,
                (AS3 void*)(vd + c * 8),
                16, 0, 0);
        }
    };

    stage(0, 0);
    unsigned long long mwn = mrowL[0];
    __syncthreads();

    int cur = 0;

    for (int kt = 0; kt < SEQ / 64; ++kt) {
        const unsigned long long mwv = mwn;

        if (kt + 1 < SEQ / 64) stage(cur ^ 1, (kt + 1) * 64);
        mwn = mrowL[(kt + 1) & (SEQ / 64 - 1)];

        const bf16* Ksb = &Ks[cur][0];
        const bf16* Vsb = &Vs[cur][0];

        // QK^T swapped: sf[nf][r] = S[key = kt*64 + nf*16 + q16*4 + r][q_l]
        f32x4 sf[4] = {};
        __builtin_amdgcn_s_setprio(1);
        #pragma unroll
        for (int c = 0; c < 4; c++) {
            #pragma unroll
            for (int nf = 0; nf < 4; nf++) {
                const bf16x8 kf = *(const bf16x8*)(
                    Ksb + (nf * 16 + l15) * 128 + (((c * 4 + q16) ^ l3) << 3));
                sf[nf] = __builtin_amdgcn_mfma_f32_16x16x32_bf16(
                    kf, qf[c], sf[nf], 0, 0, 0);
            }
        }
        __builtin_amdgcn_s_setprio(0);

        // mask: bit position of key within tile = nf*16 + q16*4 + r
        #pragma unroll
        for (int nf = 0; nf < 4; nf++)
            #pragma unroll
            for (int r = 0; r < 4; r++) {
                const int mk = (int)((mwv >> (nf * 16 + q16 * 4 + r)) & 1ull);
                sf[nf][r] = mk ? MASKV : sf[nf][r];
            }

        // per-lane softmax: in-lane max over 16 keys + 2 cross-group levels
        float t0 = fmaxf(fmaxf(sf[0][0], sf[0][1]), fmaxf(sf[0][2], sf[0][3]));
        float t1 = fmaxf(fmaxf(sf[1][0], sf[1][1]), fmaxf(sf[1][2], sf[1][3]));
        float t2 = fmaxf(fmaxf(sf[2][0], sf[2][1]), fmaxf(sf[2][2], sf[2][3]));
        float t3 = fmaxf(fmaxf(sf[3][0], sf[3][1]), fmaxf(sf[3][2], sf[3][3]));
        float mx = fmaxf(fmaxf(t0, t1), fmaxf(t2, t3));
        mx = fmaxf(mx, __shfl_xor(mx, 16));
        mx = fmaxf(mx, __shfl_xor(mx, 32));
        const float mnew  = fmaxf(m_l, mx);
        const float alpha = __builtin_amdgcn_exp2f(m_l - mnew);
        const bool  need  = mnew > m_l;
        m_l = mnew;

        float ps = 0.f;
        #pragma unroll
        for (int nf = 0; nf < 4; nf++)
            #pragma unroll
            for (int r = 0; r < 4; r++) {
                const float p = __builtin_amdgcn_exp2f(sf[nf][r] - mnew);
                sf[nf][r] = p;
                ps += p;
            }
        l_l = l_l * alpha + ps;   // per-lane partial (16 keys); merged at end

        if (__ballot(need)) {
            #pragma unroll
            for (int df = 0; df < 8; df++)
                #pragma unroll
                for (int r = 0; r < 4; r++)
                    o[df][r] *= alpha;
        }

        // P -> PV B-fragments: PURE register repack (sigma-permuted V).
        // slot (cc, q16, j) holds key (2cc+(j>>2))*16 + 4*q16 + (j&3)
        //   => pf[cc][j] = sf[2cc + (j>>2)][j&3]
        bf16x8 pf[2];
        #pragma unroll
        for (int cc = 0; cc < 2; cc++) {
            bf16x8 t;
            #pragma unroll
            for (int j = 0; j < 8; j++)
                t[j] = (bf16)sf[2 * cc + (j >> 2)][j & 3];
            pf[cc] = t;
        }

        // PV swapped: o[df] = O[d = df*16 + q16*4 + r][q_l]
        __builtin_amdgcn_s_setprio(1);
        #pragma unroll
        for (int df = 0; df < 8; df++) {
            #pragma unroll
            for (int cc = 0; cc < 2; cc++) {
                const bf16x8 vf = *(const bf16x8*)(
                    Vsb + (df * 16 + l15) * 64 + (((cc * 4 + q16) ^ l3) << 3));
                o[df] = __builtin_amdgcn_mfma_f32_16x16x32_bf16(
                    vf, pf[cc], o[df], 0, 0, 0);
            }
        }
        __builtin_amdgcn_s_setprio(0);

        __syncthreads();
        cur ^= 1;
    }

    // final l: merge the 4 per-group partials (replicated result in all lanes)
    float ls = l_l;
    ls += __shfl_xor(ls, 16);
    ls += __shfl_xor(ls, 32);
    const float linv = 1.0f / ls;

    #pragma unroll
    for (int df = 0; df < 8; df++) {
        #pragma unroll
        for (int r = 0; r < 4; r++) {
            out[((size_t)b * SEQ + q_l) * DM + h * HD + df * 16 + q16 * 4 + r] =
                o[df][r] * linv;
        }
    }
}

extern "C" void kernel_launch(void* const* d_in, const int* in_sizes, int n_in,
                              void* d_out, int out_size, void* d_ws, size_t ws_size,
                              hipStream_t stream) {
    const float* q    = (const float*)d_in[0];
    const float* k    = (const float*)d_in[1];
    const float* v    = (const float*)d_in[2];
    const void*  mask = d_in[3];
    const float* Wq   = (const float*)d_in[4];
    const float* bq   = (const float*)d_in[5];
    const float* Wk   = (const float*)d_in[6];
    const float* bk   = (const float*)d_in[7];
    const float* Wv   = (const float*)d_in[8];
    const float* bv   = (const float*)d_in[9];
    float* out = (float*)d_out;

    char* ws = (char*)d_ws;
    unsigned long long* bits = (unsigned long long*)ws;
    const size_t bits_bytes = (size_t)NB * SEQ * SEQ / 8;
    unsigned int* flag = (unsigned int*)(ws + bits_bytes);
    bf16* Qp = (bf16*)(ws + bits_bytes + 256);
    bf16* Kp = Qp + (size_t)NB * SEQ * DM;
    bf16* Vp = Kp + (size_t)NB * SEQ * DM;
    bf16* Xc = Vp + (size_t)NB * SEQ * DM;            // 24 MB
    bf16* Wt = Xc + (size_t)3 * NB * SEQ * DM;        //  6 MB

    // 3 launches: detect folded into prep (z==6), pack folded into proj (pz==3)
    prep_kernel<<<dim3(1024, 7), 256, 0, stream>>>(
        q, k, v, Wq, Wk, Wv, (const unsigned int*)mask, Xc, Wt, flag);

    dim3 pgrid(DM / 128, (NB * SEQ) / 128, 4);
    proj_kernel<<<pgrid, 256, 0, stream>>>(Xc, Wt, bq, bk, bv, Qp, Kp, Vp,
                                           mask, flag, bits);

    dim3 agrid(SEQ / 64, NH, NB);
    attn_kernel<<<agrid, 256, 0, stream>>>(Qp, Kp, Vp,
                                           (const unsigned int*)bits, out);
}